// Round 6
// baseline (325.388 us; speedup 1.0000x reference)
//
#include <hip/hip_runtime.h>

// Problem constants (fixed by the reference).
#define NNODES 100000
#define NEDGES 800000
#define DIN    128
#define HID    64
#define EMB    32
#define NIDX   50000
#define BN_EPS 1e-5f

// Direct-CSR build parameters.
#define DEGB 250                  // degree-histogram blocks (3200 edges each)
#define RB   98                   // scan blocks (1024 rows each)
#define RPAD (RB * 1024)          // 100352 padded rows (deg[] zero-padded)
#define SC   512                  // scatter blocks
#define EPB  1564                 // edges per scatter block (4-aligned, 512*1564 >= E)

typedef __attribute__((ext_vector_type(8))) short short8;   // 8 bf16 = 4 VGPR
typedef __attribute__((ext_vector_type(4))) float f32x4;    // MFMA C/D

__device__ inline unsigned short f2bf(float f) {            // RNE, matches HW
    unsigned u = __float_as_uint(f);
    unsigned r = u + 0x7FFFu + ((u >> 16) & 1u);
    return (unsigned short)(r >> 16);
}
__device__ inline float bf2f_lo(unsigned u) { return __uint_as_float(u << 16); }
__device__ inline float bf2f_hi(unsigned u) { return __uint_as_float(u & 0xffff0000u); }

// ---------------------------------------------------------------------------
// W pre-pack: fp32 [Wn|Wg] -> bf16 B-fragment-major (GEMM B-loads coalesced).
// ---------------------------------------------------------------------------

__device__ inline void pack_seg(const float* __restrict__ Wn, const float* __restrict__ Wg,
                                unsigned short* __restrict__ Wp, int HOUT, int l2nt, int f) {
    int j = f & 7, lane = (f >> 3) & 63, g = f >> 9;
    int tt = g & ((1 << l2nt) - 1), kb = g >> l2nt;
    int k = kb * 32 + ((lane >> 4) * 8) + j;
    int nn = tt * 16 + (lane & 15);
    float v = (nn < HOUT) ? Wn[k * HOUT + nn] : Wg[k * HOUT + (nn - HOUT)];
    Wp[f] = f2bf(v);
}

// ---------------------------------------------------------------------------
// K1: blocks [0,DEGB): per-row degree histogram (global atomics)
//     blocks [DEGB,DEGB+MB): mark[idx[j]] = 1
//     blocks [DEGB+MB,..): W pre-pack (all 3 layers)  -- all independent.
// ---------------------------------------------------------------------------

__global__ __launch_bounds__(256) void histpack_k(
    const int* __restrict__ rows, int* __restrict__ deg,
    const int* __restrict__ idx, int* __restrict__ mark,
    const float* Wn0, const float* Wg0, const float* Wn1,
    const float* Wg1, const float* WnL, const float* WgL,
    unsigned short* Wp0, unsigned short* Wp1, unsigned short* WpL, int MB)
{
    int blk = blockIdx.x;
    int t = threadIdx.x;
    if (blk >= DEGB + MB) {
        int f = (blk - DEGB - MB) * 256 + t;
        if (f < 16384)      pack_seg(Wn0, Wg0, Wp0, 64, 3, f);           // 128x128
        else if (f < 24576) pack_seg(Wn1, Wg1, Wp1, 64, 3, f - 16384);   // 64x128
        else if (f < 28672) pack_seg(WnL, WgL, WpL, 32, 2, f - 24576);   // 64x64
        return;
    }
    if (blk >= DEGB) {
        int j = (blk - DEGB) * 256 + t;
        if (j < NIDX) mark[idx[j]] = 1;
        return;
    }
    // degree histogram: 3200 edges per block, int4 reads
    const int* rbase = rows + blk * 3200;
    for (int i4 = t; i4 < 800; i4 += 256) {
        int4 r4 = *(const int4*)&rbase[i4 * 4];
        atomicAdd(&deg[r4.x], 1);
        atomicAdd(&deg[r4.y], 1);
        atomicAdd(&deg[r4.z], 1);
        atomicAdd(&deg[r4.w], 1);
    }
}

// rs1: per-block degree sums (1024 rows/block).
__global__ __launch_bounds__(256) void rs1_k(const int* __restrict__ deg, int* __restrict__ bsum) {
    __shared__ int s[256];
    int b = blockIdx.x, t = threadIdx.x;
    int4 d = *(const int4*)&deg[b * 1024 + t * 4];
    int loc = d.x + d.y + d.z + d.w;
    s[t] = loc;
    __syncthreads();
    for (int off = 128; off > 0; off >>= 1) {
        if (t < off) s[t] += s[t + off];
        __syncthreads();
    }
    if (t == 0) bsum[b] = s[0];
}

// rs2: exclusive scan of RB block sums.
__global__ void rs2_k(const int* __restrict__ bsum, int* __restrict__ bbase) {
    __shared__ int s[128];
    int t = threadIdx.x;
    int v = (t < RB) ? bsum[t] : 0;
    s[t] = v;
    __syncthreads();
    for (int off = 1; off < 128; off <<= 1) {
        int a = (t >= off) ? s[t - off] : 0;
        __syncthreads();
        s[t] += a;
        __syncthreads();
    }
    if (t < RB) bbase[t] = s[t] - v;
}

// rs3: full exclusive scan -> rowptr + cur (scatter cursors).
__global__ __launch_bounds__(256) void rs3_k(const int* __restrict__ deg,
                                             const int* __restrict__ bbase,
                                             int* __restrict__ rowptr,
                                             int* __restrict__ cur) {
    __shared__ int s[256];
    int b = blockIdx.x, t = threadIdx.x;
    int4 d = *(const int4*)&deg[b * 1024 + t * 4];
    int loc = d.x + d.y + d.z + d.w;
    s[t] = loc;
    __syncthreads();
    for (int off = 1; off < 256; off <<= 1) {
        int a = (t >= off) ? s[t - off] : 0;
        __syncthreads();
        s[t] += a;
        __syncthreads();
    }
    int base = bbase[b] + s[t] - loc;
    int r0 = b * 1024 + t * 4;
    if (r0 < NNODES) {                       // NNODES % 4 == 0 -> whole int4 valid
        int4 p;
        p.x = base;
        p.y = p.x + d.x;
        p.z = p.y + d.y;
        p.w = p.z + d.z;
        *(int4*)&rowptr[r0] = p;
        *(int4*)&cur[r0] = p;
    }
    if (b == RB - 1 && t == 255) rowptr[NNODES] = NEDGES;
}

// ---------------------------------------------------------------------------
// MFMA dual-GEMM body. [Hn | Hg] = act(X) @ [Wn | Wg] (+ per-col biases);
// Hg always bf16 out; Hn bf16 (HNBF) or fp32. X fp32 or bf16 (XBF).
// AFF: BN scale/shift recomputed in-block from striped sums.
// Epilogue: bf16 outputs staged through LDS (reusing Xs) -> coalesced uint4.
// ---------------------------------------------------------------------------

template <int K, int HOUT, bool AFF, bool XBF, bool HNBF>
__device__ void gemm_body(const void* __restrict__ Xv, const unsigned short* __restrict__ Wp,
                          const float* __restrict__ bnA, const float* __restrict__ bnB,
                          const float* __restrict__ bgA,
                          const float* __restrict__ sums, const float* __restrict__ gamma,
                          const float* __restrict__ beta,
                          float* __restrict__ Hnf, unsigned short* __restrict__ Hnb,
                          unsigned short* __restrict__ Hgb, int n, int blk)
{
    constexpr int NT = 2 * HOUT / 16, NKB = K / 32;
    constexpr int RS = K + 8;                       // staging row stride (shorts)
    constexpr int OC = HNBF ? 2 * HOUT : HOUT;      // cols staged through LDS in epilogue
    constexpr int RSE = OC + 8;                     // epilogue row stride (shorts, 16B mult)
    constexpr int XSZ = (RS > RSE) ? RS : RSE;
    __shared__ unsigned short Xs[64 * XSZ];
    __shared__ float sSc[64], sSh[64];

    const int row0 = blk * 64;
    const int t = threadIdx.x;

    if (AFF) {               // in-block BN finalize: 1KB of reads, once per block
        if (t < 64) {
            float sum = 0.f, sq = 0.f;
#pragma unroll
            for (int s = 0; s < 8; s++) { sum += sums[s * 128 + t]; sq += sums[s * 128 + 64 + t]; }
            float m = sum / (float)NNODES;
            float var = sq / (float)NNODES - m * m;
            float sc = gamma[t] * rsqrtf(var + BN_EPS);
            sSc[t] = sc; sSh[t] = beta[t] - m * sc;
        }
        __syncthreads();
    }

    // Stage 64 x K -> bf16 LDS. Loads batched first (row-clamped, unconditional),
    // then convert (+affine+relu) and ds_write.
    constexpr int SIT = K / 32;      // staging iterations per thread (256 thr)
    if constexpr (XBF) {
        uint4 u[SIT];
#pragma unroll
        for (int it = 0; it < SIT; it++) {
            int li = it * 256 + t;
            int rr = row0 + li / (K / 8);
            int k8 = (li % (K / 8)) * 8;
            int rc = rr < n ? rr : n - 1;
            u[it] = *(const uint4*)((const unsigned short*)Xv + (size_t)rc * K + k8);
        }
#pragma unroll
        for (int it = 0; it < SIT; it++) {
            int li = it * 256 + t;
            int r  = li / (K / 8);
            int k8 = (li % (K / 8)) * 8;
            float v[8];
            v[0] = bf2f_lo(u[it].x); v[1] = bf2f_hi(u[it].x);
            v[2] = bf2f_lo(u[it].y); v[3] = bf2f_hi(u[it].y);
            v[4] = bf2f_lo(u[it].z); v[5] = bf2f_hi(u[it].z);
            v[6] = bf2f_lo(u[it].w); v[7] = bf2f_hi(u[it].w);
            if (AFF) {
#pragma unroll
                for (int i = 0; i < 8; i++) v[i] = fmaxf(v[i] * sSc[k8 + i] + sSh[k8 + i], 0.f);
            }
            uint4 o;
            o.x = (unsigned)f2bf(v[0]) | ((unsigned)f2bf(v[1]) << 16);
            o.y = (unsigned)f2bf(v[2]) | ((unsigned)f2bf(v[3]) << 16);
            o.z = (unsigned)f2bf(v[4]) | ((unsigned)f2bf(v[5]) << 16);
            o.w = (unsigned)f2bf(v[6]) | ((unsigned)f2bf(v[7]) << 16);
            *(uint4*)&Xs[r * RS + k8] = o;
        }
    } else {
        const float* Xf = (const float*)Xv;
        float4 a[SIT], b[SIT];
#pragma unroll
        for (int it = 0; it < SIT; it++) {
            int li = it * 256 + t;
            int rr = row0 + li / (K / 8);
            int k8 = (li % (K / 8)) * 8;
            int rc = rr < n ? rr : n - 1;
            a[it] = *(const float4*)&Xf[(size_t)rc * K + k8];
            b[it] = *(const float4*)&Xf[(size_t)rc * K + k8 + 4];
        }
#pragma unroll
        for (int it = 0; it < SIT; it++) {
            int li = it * 256 + t;
            int r  = li / (K / 8);
            int k8 = (li % (K / 8)) * 8;
            float v[8] = { a[it].x, a[it].y, a[it].z, a[it].w,
                           b[it].x, b[it].y, b[it].z, b[it].w };
            if (AFF) {
#pragma unroll
                for (int i = 0; i < 8; i++) v[i] = fmaxf(v[i] * sSc[k8 + i] + sSh[k8 + i], 0.f);
            }
            uint4 o;
            o.x = (unsigned)f2bf(v[0]) | ((unsigned)f2bf(v[1]) << 16);
            o.y = (unsigned)f2bf(v[2]) | ((unsigned)f2bf(v[3]) << 16);
            o.z = (unsigned)f2bf(v[4]) | ((unsigned)f2bf(v[5]) << 16);
            o.w = (unsigned)f2bf(v[6]) | ((unsigned)f2bf(v[7]) << 16);
            *(uint4*)&Xs[r * RS + k8] = o;
        }
    }
    __syncthreads();

    const int wave = t >> 6, lane = t & 63;
    const int q = lane >> 4, mrow = lane & 15;

    f32x4 acc[NT];
#pragma unroll
    for (int i = 0; i < NT; i++) acc[i] = (f32x4){0.f, 0.f, 0.f, 0.f};

    const short8* wp8 = (const short8*)Wp;
#pragma unroll
    for (int kb = 0; kb < NKB; kb++) {
        short8 va = *(const short8*)&Xs[(wave * 16 + mrow) * RS + kb * 32 + q * 8];
#pragma unroll
        for (int tt = 0; tt < NT; tt++) {
            short8 vb = wp8[(kb * NT + tt) * 64 + lane];   // coalesced dwordx4
            acc[tt] = __builtin_amdgcn_mfma_f32_16x16x32_bf16(va, vb, acc[tt], 0, 0, 0);
        }
    }

    // Epilogue. C/D: col = lane&15 (tile tt), row = q*4 + reg.
    // bf16 outputs -> LDS (reuse Xs) -> coalesced uint4 stores.
    __syncthreads();          // all waves done reading staging Xs
#pragma unroll
    for (int tt = 0; tt < NT; tt++) {
        int nglob = tt * 16 + mrow;
        bool nside = (nglob < HOUT);
        int c = nside ? nglob : (nglob - HOUT);
        float bias = 0.f;
        if (nside) {
            if (bnA) bias += bnA[c];
            if (bnB) bias += bnB[c];
        } else if (bgA) {
            bias += bgA[c];
        }
        if (HNBF || !nside) {
            int cc = HNBF ? nglob : c;
#pragma unroll
            for (int r = 0; r < 4; r++)
                Xs[(wave * 16 + q * 4 + r) * RSE + cc] = f2bf(acc[tt][r] + bias);
        } else {
            // fp32 Hn half (last layer only): direct stores
#pragma unroll
            for (int r = 0; r < 4; r++) {
                int rr = row0 + wave * 16 + q * 4 + r;
                if (rr < n) Hnf[(size_t)rr * HOUT + c] = acc[tt][r] + bias;
            }
        }
    }
    __syncthreads();
    constexpr int J = OC / 8;                 // uint4 per row
#pragma unroll
    for (int u2 = 0; u2 < (64 * J) / 256; u2++) {
        int li = u2 * 256 + t;
        int r = li / J, j = li % J;
        int rr = row0 + r;
        if (rr < n) {
            uint4 v = *(const uint4*)&Xs[r * RSE + j * 8];
            int c8 = j * 8;
            if (HNBF && c8 < HOUT)
                *(uint4*)&Hnb[(size_t)rr * HOUT + c8] = v;
            else
                *(uint4*)&Hgb[(size_t)rr * HOUT + (HNBF ? c8 - HOUT : c8)] = v;
        }
    }
}

// K_C: blocks [0,SC): direct CSR scatter -- p = atomicAdd(&cur[row],1);
//      cs[p] = {col,val}. Each row's ~8 edges land in one contiguous 64B
//      region (write-locality == bucket sort), no ebuf round-trip, no bfinal.
//      blocks [SC,..): layer-0 dual GEMM (co-scheduled, independent).
__global__ __launch_bounds__(256) void scatter_gemm0_k(
    const int* __restrict__ rows, const int* __restrict__ cols,
    const float* __restrict__ vals, int* __restrict__ cur, int2* __restrict__ cs,
    const float* __restrict__ X, const unsigned short* __restrict__ Wp0,
    const float* __restrict__ bn0, const float* __restrict__ ab0, const float* __restrict__ bg0,
    unsigned short* __restrict__ Hn0b, unsigned short* __restrict__ Hgb, int n)
{
    if ((int)blockIdx.x < SC) {
        int blk = blockIdx.x, t = threadIdx.x;
        int e0 = blk * EPB;
        int e1 = min(e0 + EPB, NEDGES);
        for (int i = e0 + t * 4; i + 3 < e1; i += 1024) {
            int4   r4 = *(const int4*)&rows[i];
            int4   c4 = *(const int4*)&cols[i];
            float4 v4 = *(const float4*)&vals[i];
#pragma unroll
            for (int j = 0; j < 4; j++) {
                int r = (&r4.x)[j];
                int p = atomicAdd(&cur[r], 1);     // device-scope, ~8 hits/counter
                cs[p] = make_int2((&c4.x)[j], __float_as_int((&v4.x)[j]));
            }
        }
    } else {
        gemm_body<DIN, HID, false, false, true>(X, Wp0, bn0, ab0, bg0,
            nullptr, nullptr, nullptr, nullptr, Hn0b, Hgb, n, blockIdx.x - SC);
    }
}

template <int K, int HOUT, bool AFF, bool XBF, bool HNBF>
__global__ __launch_bounds__(256) void gemm_k(
    const void* __restrict__ X, const unsigned short* __restrict__ Wp,
    const float* __restrict__ bnA, const float* __restrict__ bnB, const float* __restrict__ bgA,
    const float* __restrict__ sums, const float* __restrict__ gamma, const float* __restrict__ beta,
    float* __restrict__ Hnf, unsigned short* __restrict__ Hnb, unsigned short* __restrict__ Hgb, int n)
{
    gemm_body<K, HOUT, AFF, XBF, HNBF>(X, Wp, bnA, bnB, bgA, sums, gamma, beta,
                                       Hnf, Hnb, Hgb, n, blockIdx.x);
}

// ---------------------------------------------------------------------------
// SpMM (row-sorted CSR gather): S[row] = Hn[row] + sum val*Hg[col], Hg bf16,
// register accumulation, 8-way unroll (8 outstanding L2/L3 gathers per group;
// avg degree 8 -> typical row is one 8-deep iteration).
// ---------------------------------------------------------------------------

template <int HH, bool STATS, bool SBF, bool MARKED>
__global__ __launch_bounds__(256) void spmm_k(
    const int* __restrict__ rowptr, const int2* __restrict__ cs,
    const unsigned short* __restrict__ Hgb, void* __restrict__ Sv,
    float* __restrict__ stats, const int* __restrict__ mark, int n)
{
    constexpr int L  = HH / 4;
    constexpr int GP = 256 / L;
    const int lane = threadIdx.x % L;
    const int g = threadIdx.x / L;
    const int gid = blockIdx.x * GP + g;
    const int ngroups = gridDim.x * GP;
    const int c0 = lane * 4;

    float4 sum = make_float4(0.f, 0.f, 0.f, 0.f);
    float4 sq  = make_float4(0.f, 0.f, 0.f, 0.f);
    for (int row = gid; row < n; row += ngroups) {
        if (MARKED && !mark[row]) continue;
        int e0 = rowptr[row], e1 = rowptr[row + 1];
        float4 a0, a1, a2, a3;
        if (SBF) {
            uint2 h = *(const uint2*)((const unsigned short*)Sv + (size_t)row * HH + c0);
            a0 = make_float4(bf2f_lo(h.x), bf2f_hi(h.x), bf2f_lo(h.y), bf2f_hi(h.y));
        } else {
            a0 = *(const float4*)((const float*)Sv + (size_t)row * HH + c0);
        }
        a1 = a2 = a3 = make_float4(0.f, 0.f, 0.f, 0.f);
        int e = e0;
        for (; e + 7 < e1; e += 8) {               // 8 independent gather chains
            int2 p0 = cs[e], p1 = cs[e + 1], p2 = cs[e + 2], p3 = cs[e + 3];
            int2 p4 = cs[e + 4], p5 = cs[e + 5], p6 = cs[e + 6], p7 = cs[e + 7];
            uint2 h0 = *(const uint2*)&Hgb[(size_t)p0.x * HH + c0];
            uint2 h1 = *(const uint2*)&Hgb[(size_t)p1.x * HH + c0];
            uint2 h2 = *(const uint2*)&Hgb[(size_t)p2.x * HH + c0];
            uint2 h3 = *(const uint2*)&Hgb[(size_t)p3.x * HH + c0];
            uint2 h4 = *(const uint2*)&Hgb[(size_t)p4.x * HH + c0];
            uint2 h5 = *(const uint2*)&Hgb[(size_t)p5.x * HH + c0];
            uint2 h6 = *(const uint2*)&Hgb[(size_t)p6.x * HH + c0];
            uint2 h7 = *(const uint2*)&Hgb[(size_t)p7.x * HH + c0];
            float v0 = __int_as_float(p0.y), v1 = __int_as_float(p1.y);
            float v2 = __int_as_float(p2.y), v3 = __int_as_float(p3.y);
            float v4 = __int_as_float(p4.y), v5 = __int_as_float(p5.y);
            float v6 = __int_as_float(p6.y), v7 = __int_as_float(p7.y);
            a0.x += v0 * bf2f_lo(h0.x); a0.y += v0 * bf2f_hi(h0.x);
            a0.z += v0 * bf2f_lo(h0.y); a0.w += v0 * bf2f_hi(h0.y);
            a1.x += v1 * bf2f_lo(h1.x); a1.y += v1 * bf2f_hi(h1.x);
            a1.z += v1 * bf2f_lo(h1.y); a1.w += v1 * bf2f_hi(h1.y);
            a2.x += v2 * bf2f_lo(h2.x); a2.y += v2 * bf2f_hi(h2.x);
            a2.z += v2 * bf2f_lo(h2.y); a2.w += v2 * bf2f_hi(h2.y);
            a3.x += v3 * bf2f_lo(h3.x); a3.y += v3 * bf2f_hi(h3.x);
            a3.z += v3 * bf2f_lo(h3.y); a3.w += v3 * bf2f_hi(h3.y);
            a0.x += v4 * bf2f_lo(h4.x); a0.y += v4 * bf2f_hi(h4.x);
            a0.z += v4 * bf2f_lo(h4.y); a0.w += v4 * bf2f_hi(h4.y);
            a1.x += v5 * bf2f_lo(h5.x); a1.y += v5 * bf2f_hi(h5.x);
            a1.z += v5 * bf2f_lo(h5.y); a1.w += v5 * bf2f_hi(h5.y);
            a2.x += v6 * bf2f_lo(h6.x); a2.y += v6 * bf2f_hi(h6.x);
            a2.z += v6 * bf2f_lo(h6.y); a2.w += v6 * bf2f_hi(h6.y);
            a3.x += v7 * bf2f_lo(h7.x); a3.y += v7 * bf2f_hi(h7.x);
            a3.z += v7 * bf2f_lo(h7.y); a3.w += v7 * bf2f_hi(h7.y);
        }
        for (; e + 3 < e1; e += 4) {               // 4 independent gather chains
            int2 p0 = cs[e], p1 = cs[e + 1], p2 = cs[e + 2], p3 = cs[e + 3];
            float v0 = __int_as_float(p0.y), v1 = __int_as_float(p1.y);
            float v2 = __int_as_float(p2.y), v3 = __int_as_float(p3.y);
            uint2 h0 = *(const uint2*)&Hgb[(size_t)p0.x * HH + c0];
            uint2 h1 = *(const uint2*)&Hgb[(size_t)p1.x * HH + c0];
            uint2 h2 = *(const uint2*)&Hgb[(size_t)p2.x * HH + c0];
            uint2 h3 = *(const uint2*)&Hgb[(size_t)p3.x * HH + c0];
            a0.x += v0 * bf2f_lo(h0.x); a0.y += v0 * bf2f_hi(h0.x);
            a0.z += v0 * bf2f_lo(h0.y); a0.w += v0 * bf2f_hi(h0.y);
            a1.x += v1 * bf2f_lo(h1.x); a1.y += v1 * bf2f_hi(h1.x);
            a1.z += v1 * bf2f_lo(h1.y); a1.w += v1 * bf2f_hi(h1.y);
            a2.x += v2 * bf2f_lo(h2.x); a2.y += v2 * bf2f_hi(h2.x);
            a2.z += v2 * bf2f_lo(h2.y); a2.w += v2 * bf2f_hi(h2.y);
            a3.x += v3 * bf2f_lo(h3.x); a3.y += v3 * bf2f_hi(h3.x);
            a3.z += v3 * bf2f_lo(h3.y); a3.w += v3 * bf2f_hi(h3.y);
        }
        for (; e < e1; e++) {
            int2 p = cs[e];
            float v = __int_as_float(p.y);
            uint2 h = *(const uint2*)&Hgb[(size_t)p.x * HH + c0];
            a0.x += v * bf2f_lo(h.x); a0.y += v * bf2f_hi(h.x);
            a0.z += v * bf2f_lo(h.y); a0.w += v * bf2f_hi(h.y);
        }
        float4 acc = make_float4(a0.x + a1.x + a2.x + a3.x, a0.y + a1.y + a2.y + a3.y,
                                 a0.z + a1.z + a2.z + a3.z, a0.w + a1.w + a2.w + a3.w);
        if (SBF) {
            uint2 o;
            o.x = (unsigned)f2bf(acc.x) | ((unsigned)f2bf(acc.y) << 16);
            o.y = (unsigned)f2bf(acc.z) | ((unsigned)f2bf(acc.w) << 16);
            *(uint2*)((unsigned short*)Sv + (size_t)row * HH + c0) = o;
        } else {
            *(float4*)((float*)Sv + (size_t)row * HH + c0) = acc;
        }
        if (STATS) {
            sum.x += acc.x; sum.y += acc.y; sum.z += acc.z; sum.w += acc.w;
            sq.x += acc.x * acc.x; sq.y += acc.y * acc.y;
            sq.z += acc.z * acc.z; sq.w += acc.w * acc.w;
        }
    }

    if constexpr (STATS) {
        __shared__ float rs[GP][HH];
        __shared__ float rq[GP][HH];
        *(float4*)&rs[g][c0] = sum;
        *(float4*)&rq[g][c0] = sq;
        __syncthreads();
        if (threadIdx.x < HH) {
            float a = 0.f, b = 0.f;
            for (int w = 0; w < GP; w++) { a += rs[w][threadIdx.x]; b += rq[w][threadIdx.x]; }
            int stripe = blockIdx.x & 7;
            atomicAdd(&stats[stripe * 128 + threadIdx.x], a);
            atomicAdd(&stats[stripe * 128 + HH + threadIdx.x], b);
        }
    }
}

__global__ void gather_k(const float* __restrict__ S, const int* __restrict__ idx,
                         float* __restrict__ out, int total4) {
    int j = blockIdx.x * 256 + threadIdx.x;
    if (j < total4) {
        int r = j / (EMB / 4), c4 = (j % (EMB / 4)) * 4;
        *(float4*)&out[(size_t)j * 4] = *(const float4*)&S[(size_t)idx[r] * EMB + c4];
    }
}

// ---------------------------------------------------------------------------

extern "C" void kernel_launch(void* const* d_in, const int* in_sizes, int n_in,
                              void* d_out, int out_size, void* d_ws, size_t ws_size,
                              hipStream_t stream) {
    const float* features = (const float*)d_in[0];
    const int*   rows     = (const int*)d_in[1];
    const int*   cols     = (const int*)d_in[2];
    const float* vals     = (const float*)d_in[3];
    const int*   idx      = (const int*)d_in[4];
    const float* Wn0 = (const float*)d_in[5];
    const float* bn0 = (const float*)d_in[6];
    const float* Wg0 = (const float*)d_in[7];
    const float* bg0 = (const float*)d_in[8];
    const float* ab0 = (const float*)d_in[9];
    const float* g0  = (const float*)d_in[10];
    const float* b0  = (const float*)d_in[11];
    const float* Wn1 = (const float*)d_in[12];
    const float* Wg1 = (const float*)d_in[13];
    const float* ab1 = (const float*)d_in[14];
    const float* g1  = (const float*)d_in[15];
    const float* b1  = (const float*)d_in[16];
    const float* WnL = (const float*)d_in[17];
    const float* WgL = (const float*)d_in[18];
    const float* abL = (const float*)d_in[19];
    float* out = (float*)d_out;

    // Workspace layout (~60 MB), 16B-aligned sub-buffers.
    float*          HnLf = (float*)d_ws;                        // N x EMB fp32 (HnL/SL)
    unsigned short* nA   = (unsigned short*)(HnLf + (size_t)NNODES * EMB); // Hn0/S0 bf16
    unsigned short* nB   = nA + (size_t)NNODES * HID;           // Hn1/S1 bf16
    unsigned short* Hgb  = nB + (size_t)NNODES * HID;           // Hg (all layers) bf16
    int2*  cs     = (int2*)(Hgb + (size_t)NNODES * HID);        // E (row-sorted payload)
    int*   rowptr = (int*)(cs + NEDGES);                        // N+4
    int*   cur    = rowptr + (NNODES + 4);                      // N+4 (scatter cursors)
    int*   bsum   = cur + (NNODES + 4);                         // 128
    int*   bbase  = bsum + 128;                                 // 128
    unsigned short* Wp0 = (unsigned short*)(bbase + 128);       // 16384
    unsigned short* Wp1 = Wp0 + 16384;                          // 8192
    unsigned short* WpL = Wp1 + 8192;                           // 4096
    // ---- single zeroed region: stats | mark | deg ----
    float* stats = (float*)(WpL + 4096);                        // 2304
    int*   mark  = (int*)(stats + 2304);                        // N
    int*   deg   = mark + NNODES;                               // RPAD (zero-padded)
    float* sums0 = stats;
    float* sums1 = stats + 1024;
    size_t zbytes = 2304 * 4 + (size_t)NNODES * 4 + (size_t)RPAD * 4;

    hipMemsetAsync(stats, 0, zbytes, stream);

    const int GBm = (NNODES + 63) / 64;     // 1563
    const int MB  = (NIDX + 255) / 256;     // 196

    // K1: per-row degree histogram + mark + W pre-pack (independent branches).
    histpack_k<<<DEGB + MB + 112, 256, 0, stream>>>(
        rows, deg, idx, mark, Wn0, Wg0, Wn1, Wg1, WnL, WgL, Wp0, Wp1, WpL, MB);
    // rowptr = exclusive scan of deg (3 tiny kernels).
    rs1_k<<<RB, 256, 0, stream>>>(deg, bsum);
    rs2_k<<<1, 128, 0, stream>>>(bsum, bbase);
    rs3_k<<<RB, 256, 0, stream>>>(deg, bbase, rowptr, cur);
    // Direct CSR scatter + layer-0 dual GEMM (co-scheduled).
    scatter_gemm0_k<<<SC + GBm, 256, 0, stream>>>(rows, cols, vals, cur, cs,
                                                  features, Wp0, bn0, ab0, bg0,
                                                  nA, Hgb, NNODES);

    // Layer 0 aggregate: S0 = Hn0 + A@Hg0 (bf16 in/out, stats fp32)
    spmm_k<HID, true, true, false><<<1600, 256, 0, stream>>>(rowptr, cs, Hgb, nA, sums0, nullptr, NNODES);

    // Layer 1: BN finalize folded into gemm; S1 = Hn1 + ab1 + A@Hg1
    gemm_k<HID, HID, true, true, true><<<GBm, 256, 0, stream>>>(
        nA, Wp1, ab1, nullptr, nullptr, sums0, g0, b0, nullptr, nB, Hgb, NNODES);
    spmm_k<HID, true, true, false><<<1600, 256, 0, stream>>>(rowptr, cs, Hgb, nB, sums1, nullptr, NNODES);

    // Last layer: HnL fp32; aggregate only rows referenced by idx.
    gemm_k<HID, EMB, true, true, false><<<GBm, 256, 0, stream>>>(
        nB, WpL, abL, nullptr, nullptr, sums1, g1, b1, HnLf, nullptr, Hgb, NNODES);
    spmm_k<EMB, false, false, true><<<1600, 256, 0, stream>>>(rowptr, cs, Hgb, HnLf, nullptr, mark, NNODES);

    gather_k<<<(NIDX * EMB / 4 + 255) / 256, 256, 0, stream>>>(HnLf, idx, out, NIDX * EMB / 4);
}

// Round 7
// 278.017 us; speedup vs baseline: 1.1704x; 1.1704x over previous
//
#include <hip/hip_runtime.h>

// Problem constants (fixed by the reference).
#define NNODES 100000
#define NEDGES 800000
#define DIN    128
#define HID    64
#define EMB    32
#define NIDX   50000
#define BN_EPS 1e-5f

#define NCHK 64                   // partition chunks (64 -> ~8-edge runs per bucket, 64B)
#define EC   (NEDGES / NCHK)      // 12500 edges per chunk
#define SUBC 256                  // histogram sub-chunks
#define ECS  (NEDGES / SUBC)      // 3125
#define SPC  (SUBC / NCHK)        // sub-chunks per chunk = 4
#define NB   ((NNODES + 63) / 64) // 1563 row-buckets of 64 rows
#define PF   16                   // bucket fractions per chunk (scatter parallelism)
#define NBF  ((NB + PF - 1) / PF) // 98 buckets per fraction

typedef __attribute__((ext_vector_type(8))) short short8;   // 8 bf16 = 4 VGPR
typedef __attribute__((ext_vector_type(4))) float f32x4;    // MFMA C/D

__device__ inline unsigned short f2bf(float f) {            // RNE, matches HW
    unsigned u = __float_as_uint(f);
    unsigned r = u + 0x7FFFu + ((u >> 16) & 1u);
    return (unsigned short)(r >> 16);
}
__device__ inline float bf2f_lo(unsigned u) { return __uint_as_float(u << 16); }
__device__ inline float bf2f_hi(unsigned u) { return __uint_as_float(u & 0xffff0000u); }

// ---------------------------------------------------------------------------
// W pre-pack: fp32 [Wn|Wg] -> bf16 B-fragment-major (GEMM B-loads coalesced).
// ---------------------------------------------------------------------------

__device__ inline void pack_seg(const float* __restrict__ Wn, const float* __restrict__ Wg,
                                unsigned short* __restrict__ Wp, int HOUT, int l2nt, int f) {
    int j = f & 7, lane = (f >> 3) & 63, g = f >> 9;
    int tt = g & ((1 << l2nt) - 1), kb = g >> l2nt;
    int k = kb * 32 + ((lane >> 4) * 8) + j;
    int nn = tt * 16 + (lane & 15);
    float v = (nn < HOUT) ? Wn[k * HOUT + nn] : Wg[k * HOUT + (nn - HOUT)];
    Wp[f] = f2bf(v);
}

// ---------------------------------------------------------------------------
// K1: blocks [0,SUBC): bucket histogram -> Bcnt4[sub][b]
//     blocks [SUBC,SUBC+MB): mark[idx[j]] = 1
//     blocks [SUBC+MB,..): W pre-pack (all 3 layers)  -- all independent.
// ---------------------------------------------------------------------------

__global__ __launch_bounds__(256) void histpack_k(
    const int* __restrict__ rows, int* __restrict__ Bcnt4,
    const int* __restrict__ idx, int* __restrict__ mark,
    const float* Wn0, const float* Wg0, const float* Wn1,
    const float* Wg1, const float* WnL, const float* WgL,
    unsigned short* Wp0, unsigned short* Wp1, unsigned short* WpL, int MB)
{
    int blk = blockIdx.x;
    if (blk >= SUBC + MB) {
        int f = (blk - SUBC - MB) * 256 + threadIdx.x;
        if (f < 16384)      pack_seg(Wn0, Wg0, Wp0, 64, 3, f);           // 128x128
        else if (f < 24576) pack_seg(Wn1, Wg1, Wp1, 64, 3, f - 16384);   // 64x128
        else if (f < 28672) pack_seg(WnL, WgL, WpL, 32, 2, f - 24576);   // 64x64
        return;
    }
    if (blk >= SUBC) {
        int j = (blk - SUBC) * 256 + threadIdx.x;
        if (j < NIDX) mark[idx[j]] = 1;
        return;
    }
    __shared__ int hist[NB];
    int t = threadIdx.x;
    for (int b = t; b < NB; b += 256) hist[b] = 0;
    __syncthreads();
    for (int i = t; i < ECS; i += 256)
        atomicAdd(&hist[rows[blk * ECS + i] >> 6], 1);
    __syncthreads();
    for (int b = t; b < NB; b += 256) Bcnt4[blk * NB + b] = hist[b];
}

__global__ void bprefix_k(const int* __restrict__ Bcnt4, int* __restrict__ BcntT,
                          int* __restrict__ bTot) {
    int b = blockIdx.x * 256 + threadIdx.x;
    if (b >= NB) return;
    int run = 0;
    for (int sub = 0; sub < SUBC; sub++) {
        if ((sub & (SPC - 1)) == 0)
            BcntT[(sub / SPC) * NB + b] = run;   // coalesced read & write
        run += Bcnt4[sub * NB + b];
    }
    bTot[b] = run;
}

__global__ void bscan_k(const int* __restrict__ bTot, int* __restrict__ bBase) {
    __shared__ int s[256];
    int t = threadIdx.x;
    int v[7], loc = 0;
#pragma unroll
    for (int i = 0; i < 7; i++) {
        int ix = t * 7 + i;
        v[i] = loc;
        loc += (ix < NB) ? bTot[ix] : 0;
    }
    s[t] = loc;
    __syncthreads();
    for (int off = 1; off < 256; off <<= 1) {
        int a = (t >= off) ? s[t - off] : 0;
        __syncthreads();
        s[t] += a;
        __syncthreads();
    }
    int base = s[t] - loc;
#pragma unroll
    for (int i = 0; i < 7; i++) {
        int ix = t * 7 + i;
        if (ix < NB) bBase[ix] = base + v[i];
    }
    if (t == 255) bBase[NB] = NEDGES;
}

// bfinal: one block per bucket (64 rows, ~512 edges): LDS 64-bin hist + scan
//         -> rowptr; scatter {col,val} into final row-sorted cs.
// ebuf entry: x = (row&63)<<20 | col, y = val bits  (8 B/edge).
__global__ __launch_bounds__(256) void bfinal_k(const uint2* __restrict__ ebuf,
                                                const int* __restrict__ bBase,
                                                int* __restrict__ rowptr,
                                                int2* __restrict__ cs) {
    __shared__ int hist[64], sc[64], cur[64];
    int b = blockIdx.x, t = threadIdx.x;
    int e0 = bBase[b], e1 = bBase[b + 1];
    int r0 = b << 6;
    if (t < 64) hist[t] = 0;
    __syncthreads();
    for (int i = e0 + t; i < e1; i += 256)
        atomicAdd(&hist[(ebuf[i].x >> 20) & 63], 1);
    __syncthreads();
    if (t == 0) {
        int run = e0;
        for (int j = 0; j < 64; j++) { sc[j] = run; run += hist[j]; }
    }
    __syncthreads();
    if (t < 64) {
        cur[t] = sc[t];
        int r = r0 + t;
        if (r < NNODES) rowptr[r] = sc[t];
    }
    if (b == NB - 1 && t == 0) rowptr[NNODES] = NEDGES;
    __syncthreads();
    for (int i = e0 + t; i < e1; i += 256) {
        uint2 v = ebuf[i];
        int p = atomicAdd(&cur[(v.x >> 20) & 63], 1);
        cs[p] = make_int2((int)(v.x & 0xFFFFF), (int)v.y);
    }
}

// ---------------------------------------------------------------------------
// MFMA dual-GEMM body. [Hn | Hg] = act(X) @ [Wn | Wg] (+ per-col biases);
// Hg always bf16 out; Hn bf16 (HNBF) or fp32. X fp32 or bf16 (XBF).
// AFF: BN scale/shift recomputed in-block from striped sums.
// Epilogue: bf16 outputs staged through LDS (reusing Xs) -> coalesced uint4.
// ---------------------------------------------------------------------------

template <int K, int HOUT, bool AFF, bool XBF, bool HNBF>
__device__ void gemm_body(const void* __restrict__ Xv, const unsigned short* __restrict__ Wp,
                          const float* __restrict__ bnA, const float* __restrict__ bnB,
                          const float* __restrict__ bgA,
                          const float* __restrict__ sums, const float* __restrict__ gamma,
                          const float* __restrict__ beta,
                          float* __restrict__ Hnf, unsigned short* __restrict__ Hnb,
                          unsigned short* __restrict__ Hgb, int n, int blk)
{
    constexpr int NT = 2 * HOUT / 16, NKB = K / 32;
    constexpr int RS = K + 8;                       // staging row stride (shorts)
    constexpr int OC = HNBF ? 2 * HOUT : HOUT;      // cols staged through LDS in epilogue
    constexpr int RSE = OC + 8;                     // epilogue row stride (shorts, 16B mult)
    constexpr int XSZ = (RS > RSE) ? RS : RSE;
    __shared__ unsigned short Xs[64 * XSZ];
    __shared__ float sSc[64], sSh[64];

    const int row0 = blk * 64;
    const int t = threadIdx.x;

    if (AFF) {               // in-block BN finalize: 1KB of reads, once per block
        if (t < 64) {
            float sum = 0.f, sq = 0.f;
#pragma unroll
            for (int s = 0; s < 8; s++) { sum += sums[s * 128 + t]; sq += sums[s * 128 + 64 + t]; }
            float m = sum / (float)NNODES;
            float var = sq / (float)NNODES - m * m;
            float sc = gamma[t] * rsqrtf(var + BN_EPS);
            sSc[t] = sc; sSh[t] = beta[t] - m * sc;
        }
        __syncthreads();
    }

    // Stage 64 x K -> bf16 LDS. Loads batched first (row-clamped, unconditional),
    // then convert (+affine+relu) and ds_write.
    constexpr int SIT = K / 32;      // staging iterations per thread (256 thr)
    if constexpr (XBF) {
        uint4 u[SIT];
#pragma unroll
        for (int it = 0; it < SIT; it++) {
            int li = it * 256 + t;
            int rr = row0 + li / (K / 8);
            int k8 = (li % (K / 8)) * 8;
            int rc = rr < n ? rr : n - 1;
            u[it] = *(const uint4*)((const unsigned short*)Xv + (size_t)rc * K + k8);
        }
#pragma unroll
        for (int it = 0; it < SIT; it++) {
            int li = it * 256 + t;
            int r  = li / (K / 8);
            int k8 = (li % (K / 8)) * 8;
            float v[8];
            v[0] = bf2f_lo(u[it].x); v[1] = bf2f_hi(u[it].x);
            v[2] = bf2f_lo(u[it].y); v[3] = bf2f_hi(u[it].y);
            v[4] = bf2f_lo(u[it].z); v[5] = bf2f_hi(u[it].z);
            v[6] = bf2f_lo(u[it].w); v[7] = bf2f_hi(u[it].w);
            if (AFF) {
#pragma unroll
                for (int i = 0; i < 8; i++) v[i] = fmaxf(v[i] * sSc[k8 + i] + sSh[k8 + i], 0.f);
            }
            uint4 o;
            o.x = (unsigned)f2bf(v[0]) | ((unsigned)f2bf(v[1]) << 16);
            o.y = (unsigned)f2bf(v[2]) | ((unsigned)f2bf(v[3]) << 16);
            o.z = (unsigned)f2bf(v[4]) | ((unsigned)f2bf(v[5]) << 16);
            o.w = (unsigned)f2bf(v[6]) | ((unsigned)f2bf(v[7]) << 16);
            *(uint4*)&Xs[r * RS + k8] = o;
        }
    } else {
        const float* Xf = (const float*)Xv;
        float4 a[SIT], b[SIT];
#pragma unroll
        for (int it = 0; it < SIT; it++) {
            int li = it * 256 + t;
            int rr = row0 + li / (K / 8);
            int k8 = (li % (K / 8)) * 8;
            int rc = rr < n ? rr : n - 1;
            a[it] = *(const float4*)&Xf[(size_t)rc * K + k8];
            b[it] = *(const float4*)&Xf[(size_t)rc * K + k8 + 4];
        }
#pragma unroll
        for (int it = 0; it < SIT; it++) {
            int li = it * 256 + t;
            int r  = li / (K / 8);
            int k8 = (li % (K / 8)) * 8;
            float v[8] = { a[it].x, a[it].y, a[it].z, a[it].w,
                           b[it].x, b[it].y, b[it].z, b[it].w };
            if (AFF) {
#pragma unroll
                for (int i = 0; i < 8; i++) v[i] = fmaxf(v[i] * sSc[k8 + i] + sSh[k8 + i], 0.f);
            }
            uint4 o;
            o.x = (unsigned)f2bf(v[0]) | ((unsigned)f2bf(v[1]) << 16);
            o.y = (unsigned)f2bf(v[2]) | ((unsigned)f2bf(v[3]) << 16);
            o.z = (unsigned)f2bf(v[4]) | ((unsigned)f2bf(v[5]) << 16);
            o.w = (unsigned)f2bf(v[6]) | ((unsigned)f2bf(v[7]) << 16);
            *(uint4*)&Xs[r * RS + k8] = o;
        }
    }
    __syncthreads();

    const int wave = t >> 6, lane = t & 63;
    const int q = lane >> 4, mrow = lane & 15;

    f32x4 acc[NT];
#pragma unroll
    for (int i = 0; i < NT; i++) acc[i] = (f32x4){0.f, 0.f, 0.f, 0.f};

    const short8* wp8 = (const short8*)Wp;
#pragma unroll
    for (int kb = 0; kb < NKB; kb++) {
        short8 va = *(const short8*)&Xs[(wave * 16 + mrow) * RS + kb * 32 + q * 8];
#pragma unroll
        for (int tt = 0; tt < NT; tt++) {
            short8 vb = wp8[(kb * NT + tt) * 64 + lane];   // coalesced dwordx4
            acc[tt] = __builtin_amdgcn_mfma_f32_16x16x32_bf16(va, vb, acc[tt], 0, 0, 0);
        }
    }

    // Epilogue. C/D: col = lane&15 (tile tt), row = q*4 + reg.
    // bf16 outputs -> LDS (reuse Xs) -> coalesced uint4 stores.
    __syncthreads();          // all waves done reading staging Xs
#pragma unroll
    for (int tt = 0; tt < NT; tt++) {
        int nglob = tt * 16 + mrow;
        bool nside = (nglob < HOUT);
        int c = nside ? nglob : (nglob - HOUT);
        float bias = 0.f;
        if (nside) {
            if (bnA) bias += bnA[c];
            if (bnB) bias += bnB[c];
        } else if (bgA) {
            bias += bgA[c];
        }
        if (HNBF || !nside) {
            int cc = HNBF ? nglob : c;
#pragma unroll
            for (int r = 0; r < 4; r++)
                Xs[(wave * 16 + q * 4 + r) * RSE + cc] = f2bf(acc[tt][r] + bias);
        } else {
            // fp32 Hn half (last layer only): direct stores
#pragma unroll
            for (int r = 0; r < 4; r++) {
                int rr = row0 + wave * 16 + q * 4 + r;
                if (rr < n) Hnf[(size_t)rr * HOUT + c] = acc[tt][r] + bias;
            }
        }
    }
    __syncthreads();
    constexpr int J = OC / 8;                 // uint4 per row
#pragma unroll
    for (int u2 = 0; u2 < (64 * J) / 256; u2++) {
        int li = u2 * 256 + t;
        int r = li / J, j = li % J;
        int rr = row0 + r;
        if (rr < n) {
            uint4 v = *(const uint4*)&Xs[r * RSE + j * 8];
            int c8 = j * 8;
            if (HNBF && c8 < HOUT)
                *(uint4*)&Hnb[(size_t)rr * HOUT + c8] = v;
            else
                *(uint4*)&Hgb[(size_t)rr * HOUT + (HNBF ? c8 - HOUT : c8)] = v;
        }
    }
}

// K_C: blocks [0,NCHK*PF): bucket-partition. Each chunk is handled by PF
//      blocks; sibling blocks are mapped chunk = i % NCHK, pf = i / NCHK so
//      all PF siblings of a chunk share i%8 (same XCD under round-robin
//      dispatch) -> the chunk's rows/cols/vals are fetched once per XCD L2.
//      rows+cols+vals streamed as coalesced int4/float4.
//      blocks [NCHK*PF,..): layer-0 dual GEMM (co-scheduled, independent).
__global__ __launch_bounds__(256) void part_gemm0_k(
    const int* __restrict__ rows, const int* __restrict__ cols,
    const float* __restrict__ vals, const int* __restrict__ BcntT,
    const int* __restrict__ bBase, uint2* __restrict__ ebuf,
    const float* __restrict__ X, const unsigned short* __restrict__ Wp0,
    const float* __restrict__ bn0, const float* __restrict__ ab0, const float* __restrict__ bg0,
    unsigned short* __restrict__ Hn0b, unsigned short* __restrict__ Hgb, int n)
{
    if ((int)blockIdx.x < NCHK * PF) {
        __shared__ int cur[NBF];
        int t = threadIdx.x;
        int blk = blockIdx.x % NCHK;          // sibling co-location: i%8 == blk%8
        int pf  = blockIdx.x / NCHK;
        int b0 = pf * NBF, b1 = (pf == PF - 1) ? NB : (b0 + NBF);
        for (int b = b0 + t; b < b1; b += 256)
            cur[b - b0] = bBase[b] + BcntT[blk * NB + b];
        __syncthreads();
        constexpr int EC4 = EC / 4;           // 3125 int4 reads per chunk stream
        const int*   rbase = rows + blk * EC;
        const int*   cbase = cols + blk * EC;
        const float* vbase = vals + blk * EC;
        for (int i4 = t; i4 < EC4; i4 += 256) {
            int4   r4 = *(const int4*)&rbase[i4 * 4];
            int4   c4 = *(const int4*)&cbase[i4 * 4];
            float4 v4 = *(const float4*)&vbase[i4 * 4];
#pragma unroll
            for (int j = 0; j < 4; j++) {
                int r = (&r4.x)[j];
                int b = r >> 6;
                if (b >= b0 && b < b1) {
                    int p = atomicAdd(&cur[b - b0], 1);    // LDS atomic
                    ebuf[p] = make_uint2(((unsigned)(r & 63) << 20) | (unsigned)(&c4.x)[j],
                                         (unsigned)__float_as_int((&v4.x)[j]));
                }
            }
        }
    } else {
        gemm_body<DIN, HID, false, false, true>(X, Wp0, bn0, ab0, bg0,
            nullptr, nullptr, nullptr, nullptr, Hn0b, Hgb, n, blockIdx.x - NCHK * PF);
    }
}

template <int K, int HOUT, bool AFF, bool XBF, bool HNBF>
__global__ __launch_bounds__(256) void gemm_k(
    const void* __restrict__ X, const unsigned short* __restrict__ Wp,
    const float* __restrict__ bnA, const float* __restrict__ bnB, const float* __restrict__ bgA,
    const float* __restrict__ sums, const float* __restrict__ gamma, const float* __restrict__ beta,
    float* __restrict__ Hnf, unsigned short* __restrict__ Hnb, unsigned short* __restrict__ Hgb, int n)
{
    gemm_body<K, HOUT, AFF, XBF, HNBF>(X, Wp, bnA, bnB, bgA, sums, gamma, beta,
                                       Hnf, Hnb, Hgb, n, blockIdx.x);
}

// ---------------------------------------------------------------------------
// SpMM v2 (block-local CSR staging): each block owns 64 CONSECUTIVE rows;
// stages rowptr[65] + the block's whole edge segment (~512 edges) into LDS
// with coalesced loads; groups then read edges from LDS (broadcast,
// conflict-free) and issue only the Hgb gathers. Serial chain per row:
// 3 global hops -> 1. Overflow (>1024 edges/block, >20 sigma) falls back
// to direct global reads per row.
// ---------------------------------------------------------------------------

template <int HH, bool STATS, bool SBF, bool MARKED>
__global__ __launch_bounds__(256) void spmm_k(
    const int* __restrict__ rowptr, const int2* __restrict__ cs,
    const unsigned short* __restrict__ Hgb, void* __restrict__ Sv,
    float* __restrict__ stats, const int* __restrict__ mark, int n)
{
    constexpr int L   = HH / 4;     // lanes per group (16 or 8)
    constexpr int GP  = 256 / L;    // groups per block (16 or 32)
    constexpr int RPB = 64;         // rows per block (consecutive)
    constexpr int RPG = RPB / GP;   // rows per group (4 or 2)
    constexpr int ECAP = 1024;      // staged-edge capacity (8KB)
    __shared__ int2 es[ECAP];
    __shared__ int  rp[RPB + 1];

    const int t = threadIdx.x;
    const int R0 = blockIdx.x * RPB;
    if (t <= RPB) rp[t] = rowptr[min(R0 + t, n)];
    __syncthreads();
    const int e0b  = rp[0];
    const int scnt = min(rp[RPB] - e0b, ECAP);
    for (int i = t; i < scnt; i += 256) es[i] = cs[e0b + i];   // coalesced 8B
    __syncthreads();

    const int lane = t % L;
    const int g    = t / L;
    const int c0   = lane * 4;

    float4 sum = make_float4(0.f, 0.f, 0.f, 0.f);
    float4 sq  = make_float4(0.f, 0.f, 0.f, 0.f);

#define SPMM_ROW(FETCH)                                                            \
    {                                                                              \
        int e = le0;                                                               \
        for (; e + 3 < le1; e += 4) {                                              \
            int2 p0 = FETCH(e), p1 = FETCH(e + 1), p2 = FETCH(e + 2), p3 = FETCH(e + 3); \
            float v0 = __int_as_float(p0.y), v1 = __int_as_float(p1.y);            \
            float v2 = __int_as_float(p2.y), v3 = __int_as_float(p3.y);            \
            uint2 h0 = *(const uint2*)&Hgb[(size_t)p0.x * HH + c0];                \
            uint2 h1 = *(const uint2*)&Hgb[(size_t)p1.x * HH + c0];                \
            uint2 h2 = *(const uint2*)&Hgb[(size_t)p2.x * HH + c0];                \
            uint2 h3 = *(const uint2*)&Hgb[(size_t)p3.x * HH + c0];                \
            a0.x += v0 * bf2f_lo(h0.x); a0.y += v0 * bf2f_hi(h0.x);                \
            a0.z += v0 * bf2f_lo(h0.y); a0.w += v0 * bf2f_hi(h0.y);                \
            a1.x += v1 * bf2f_lo(h1.x); a1.y += v1 * bf2f_hi(h1.x);                \
            a1.z += v1 * bf2f_lo(h1.y); a1.w += v1 * bf2f_hi(h1.y);                \
            a2.x += v2 * bf2f_lo(h2.x); a2.y += v2 * bf2f_hi(h2.x);                \
            a2.z += v2 * bf2f_lo(h2.y); a2.w += v2 * bf2f_hi(h2.y);                \
            a3.x += v3 * bf2f_lo(h3.x); a3.y += v3 * bf2f_hi(h3.x);                \
            a3.z += v3 * bf2f_lo(h3.y); a3.w += v3 * bf2f_hi(h3.y);                \
        }                                                                          \
        for (; e < le1; e++) {                                                     \
            int2 p = FETCH(e);                                                     \
            float v = __int_as_float(p.y);                                         \
            uint2 h = *(const uint2*)&Hgb[(size_t)p.x * HH + c0];                  \
            a0.x += v * bf2f_lo(h.x); a0.y += v * bf2f_hi(h.x);                    \
            a0.z += v * bf2f_lo(h.y); a0.w += v * bf2f_hi(h.y);                    \
        }                                                                          \
    }
#define F_LDS(i) es[(i)]
#define F_GLB(i) cs[e0b + (i)]

#pragma unroll
    for (int rr = 0; rr < RPG; rr++) {
        int row = R0 + g * RPG + rr;
        if (row >= n) break;
        if (MARKED && !mark[row]) continue;
        int le0 = rp[g * RPG + rr] - e0b;
        int le1 = rp[g * RPG + rr + 1] - e0b;
        float4 a0, a1, a2, a3;
        if (SBF) {
            uint2 h = *(const uint2*)((const unsigned short*)Sv + (size_t)row * HH + c0);
            a0 = make_float4(bf2f_lo(h.x), bf2f_hi(h.x), bf2f_lo(h.y), bf2f_hi(h.y));
        } else {
            a0 = *(const float4*)((const float*)Sv + (size_t)row * HH + c0);
        }
        a1 = a2 = a3 = make_float4(0.f, 0.f, 0.f, 0.f);
        if (le1 <= scnt) SPMM_ROW(F_LDS) else SPMM_ROW(F_GLB);
        float4 acc = make_float4(a0.x + a1.x + a2.x + a3.x, a0.y + a1.y + a2.y + a3.y,
                                 a0.z + a1.z + a2.z + a3.z, a0.w + a1.w + a2.w + a3.w);
        if (SBF) {
            uint2 o;
            o.x = (unsigned)f2bf(acc.x) | ((unsigned)f2bf(acc.y) << 16);
            o.y = (unsigned)f2bf(acc.z) | ((unsigned)f2bf(acc.w) << 16);
            *(uint2*)((unsigned short*)Sv + (size_t)row * HH + c0) = o;
        } else {
            *(float4*)((float*)Sv + (size_t)row * HH + c0) = acc;
        }
        if (STATS) {
            sum.x += acc.x; sum.y += acc.y; sum.z += acc.z; sum.w += acc.w;
            sq.x += acc.x * acc.x; sq.y += acc.y * acc.y;
            sq.z += acc.z * acc.z; sq.w += acc.w * acc.w;
        }
    }
#undef SPMM_ROW
#undef F_LDS
#undef F_GLB

    if constexpr (STATS) {
        __shared__ float rs[GP][HH];
        __shared__ float rq[GP][HH];
        *(float4*)&rs[g][c0] = sum;
        *(float4*)&rq[g][c0] = sq;
        __syncthreads();
        if (threadIdx.x < HH) {
            float a = 0.f, b = 0.f;
            for (int w = 0; w < GP; w++) { a += rs[w][threadIdx.x]; b += rq[w][threadIdx.x]; }
            int stripe = blockIdx.x & 7;
            atomicAdd(&stats[stripe * 128 + threadIdx.x], a);
            atomicAdd(&stats[stripe * 128 + HH + threadIdx.x], b);
        }
    }
}

__global__ void gather_k(const float* __restrict__ S, const int* __restrict__ idx,
                         float* __restrict__ out, int total4) {
    int j = blockIdx.x * 256 + threadIdx.x;
    if (j < total4) {
        int r = j / (EMB / 4), c4 = (j % (EMB / 4)) * 4;
        *(float4*)&out[(size_t)j * 4] = *(const float4*)&S[(size_t)idx[r] * EMB + c4];
    }
}

// ---------------------------------------------------------------------------

extern "C" void kernel_launch(void* const* d_in, const int* in_sizes, int n_in,
                              void* d_out, int out_size, void* d_ws, size_t ws_size,
                              hipStream_t stream) {
    const float* features = (const float*)d_in[0];
    const int*   rows     = (const int*)d_in[1];
    const int*   cols     = (const int*)d_in[2];
    const float* vals     = (const float*)d_in[3];
    const int*   idx      = (const int*)d_in[4];
    const float* Wn0 = (const float*)d_in[5];
    const float* bn0 = (const float*)d_in[6];
    const float* Wg0 = (const float*)d_in[7];
    const float* bg0 = (const float*)d_in[8];
    const float* ab0 = (const float*)d_in[9];
    const float* g0  = (const float*)d_in[10];
    const float* b0  = (const float*)d_in[11];
    const float* Wn1 = (const float*)d_in[12];
    const float* Wg1 = (const float*)d_in[13];
    const float* ab1 = (const float*)d_in[14];
    const float* g1  = (const float*)d_in[15];
    const float* b1  = (const float*)d_in[16];
    const float* WnL = (const float*)d_in[17];
    const float* WgL = (const float*)d_in[18];
    const float* abL = (const float*)d_in[19];
    float* out = (float*)d_out;

    // Workspace layout (~70 MB), 16B-aligned sub-buffers.
    float*          HnLf = (float*)d_ws;                        // N x EMB fp32 (HnL/SL)
    unsigned short* nA   = (unsigned short*)(HnLf + (size_t)NNODES * EMB); // Hn0/S0 bf16
    unsigned short* nB   = nA + (size_t)NNODES * HID;           // Hn1/S1 bf16
    unsigned short* Hgb  = nB + (size_t)NNODES * HID;           // Hg (all layers) bf16
    uint2* ebuf  = (uint2*)(Hgb + (size_t)NNODES * HID);        // E x 8B (packed)
    int2*  cs    = (int2*)(ebuf + NEDGES);                      // E (row-sorted payload)
    int*   rowptr = (int*)(cs + NEDGES);                        // N+4
    int*   Bcnt4 = rowptr + (NNODES + 4);                       // SUBC x NB
    int*   BcntT = Bcnt4 + SUBC * NB;                           // NCHK x NB
    int*   bTot  = BcntT + NCHK * NB;                           // NB (pad 1568)
    int*   bBase = bTot + 1568;                                 // NB+1 (pad 1568)
    unsigned short* Wp0 = (unsigned short*)(bBase + 1568);      // 16384
    unsigned short* Wp1 = Wp0 + 16384;                          // 8192
    unsigned short* WpL = Wp1 + 8192;                           // 4096
    // ---- single zeroed region: stats | mark ----
    float* stats = (float*)(WpL + 4096);                        // 2304
    int*   mark  = (int*)(stats + 2304);                        // N
    float* sums0 = stats;
    float* sums1 = stats + 1024;
    size_t zbytes = 2304 * 4 + (size_t)NNODES * 4;

    hipMemsetAsync(stats, 0, zbytes, stream);

    const int GBm = (NNODES + 63) / 64;     // 1563
    const int MB  = (NIDX + 255) / 256;     // 196

    // K1: bucket histogram + mark + W pre-pack (independent branches).
    histpack_k<<<SUBC + MB + 112, 256, 0, stream>>>(
        rows, Bcnt4, idx, mark, Wn0, Wg0, Wn1, Wg1, WnL, WgL, Wp0, Wp1, WpL, MB);
    bprefix_k<<<7, 256, 0, stream>>>(Bcnt4, BcntT, bTot);
    bscan_k<<<1, 256, 0, stream>>>(bTot, bBase);
    part_gemm0_k<<<NCHK * PF + GBm, 256, 0, stream>>>(rows, cols, vals, BcntT, bBase, ebuf,
                                                      features, Wp0, bn0, ab0, bg0,
                                                      nA, Hgb, NNODES);
    bfinal_k<<<NB, 256, 0, stream>>>(ebuf, bBase, rowptr, cs);

    // Layer 0 aggregate: S0 = Hn0 + A@Hg0 (bf16 in/out, stats fp32)
    spmm_k<HID, true, true, false><<<GBm, 256, 0, stream>>>(rowptr, cs, Hgb, nA, sums0, nullptr, NNODES);

    // Layer 1: BN finalize folded into gemm; S1 = Hn1 + ab1 + A@Hg1
    gemm_k<HID, HID, true, true, true><<<GBm, 256, 0, stream>>>(
        nA, Wp1, ab1, nullptr, nullptr, sums0, g0, b0, nullptr, nB, Hgb, NNODES);
    spmm_k<HID, true, true, false><<<GBm, 256, 0, stream>>>(rowptr, cs, Hgb, nB, sums1, nullptr, NNODES);

    // Last layer: HnL fp32; aggregate only rows referenced by idx.
    gemm_k<HID, EMB, true, true, false><<<GBm, 256, 0, stream>>>(
        nB, WpL, abL, nullptr, nullptr, sums1, g1, b1, HnLf, nullptr, Hgb, NNODES);
    spmm_k<EMB, false, false, true><<<GBm, 256, 0, stream>>>(rowptr, cs, Hgb, HnLf, nullptr, mark, NNODES);

    gather_k<<<(NIDX * EMB / 4 + 255) / 256, 256, 0, stream>>>(HnLf, idx, out, NIDX * EMB / 4);
}

// Round 8
// 276.029 us; speedup vs baseline: 1.1788x; 1.0072x over previous
//
#include <hip/hip_runtime.h>

// Problem constants (fixed by the reference).
#define NNODES 100000
#define NEDGES 800000
#define DIN    128
#define HID    64
#define EMB    32
#define NIDX   50000
#define BN_EPS 1e-5f

#define NCHK 64                   // partition chunks (64 -> ~8-edge runs per bucket, 64B)
#define EC   (NEDGES / NCHK)      // 12500 edges per chunk
#define SUBC 256                  // histogram sub-chunks
#define ECS  (NEDGES / SUBC)      // 3125
#define SPC  (SUBC / NCHK)        // sub-chunks per chunk = 4
#define NB   ((NNODES + 63) / 64) // 1563 row-buckets of 64 rows
#define PF   16                   // bucket fractions per chunk (scatter parallelism)
#define NBF  ((NB + PF - 1) / PF) // 98 buckets per fraction

typedef __attribute__((ext_vector_type(8))) short short8;   // 8 bf16 = 4 VGPR
typedef __attribute__((ext_vector_type(4))) float f32x4;    // MFMA C/D

__device__ inline unsigned short f2bf(float f) {            // RNE, matches HW
    unsigned u = __float_as_uint(f);
    unsigned r = u + 0x7FFFu + ((u >> 16) & 1u);
    return (unsigned short)(r >> 16);
}
__device__ inline float bf2f_lo(unsigned u) { return __uint_as_float(u << 16); }
__device__ inline float bf2f_hi(unsigned u) { return __uint_as_float(u & 0xffff0000u); }

// ---------------------------------------------------------------------------
// W pre-pack: fp32 [Wn|Wg] -> bf16 B-fragment-major (GEMM B-loads coalesced).
// ---------------------------------------------------------------------------

__device__ inline void pack_seg(const float* __restrict__ Wn, const float* __restrict__ Wg,
                                unsigned short* __restrict__ Wp, int HOUT, int l2nt, int f) {
    int j = f & 7, lane = (f >> 3) & 63, g = f >> 9;
    int tt = g & ((1 << l2nt) - 1), kb = g >> l2nt;
    int k = kb * 32 + ((lane >> 4) * 8) + j;
    int nn = tt * 16 + (lane & 15);
    float v = (nn < HOUT) ? Wn[k * HOUT + nn] : Wg[k * HOUT + (nn - HOUT)];
    Wp[f] = f2bf(v);
}

// ---------------------------------------------------------------------------
// K1: blocks [0,SUBC): bucket histogram -> Bcnt4[sub][b]
//     blocks [SUBC,SUBC+MB): mark[idx[j]] = 1
//     blocks [SUBC+MB,..): W pre-pack (all 3 layers)  -- all independent.
// ---------------------------------------------------------------------------

__global__ __launch_bounds__(256) void histpack_k(
    const int* __restrict__ rows, int* __restrict__ Bcnt4,
    const int* __restrict__ idx, int* __restrict__ mark,
    const float* Wn0, const float* Wg0, const float* Wn1,
    const float* Wg1, const float* WnL, const float* WgL,
    unsigned short* Wp0, unsigned short* Wp1, unsigned short* WpL, int MB)
{
    int blk = blockIdx.x;
    if (blk >= SUBC + MB) {
        int f = (blk - SUBC - MB) * 256 + threadIdx.x;
        if (f < 16384)      pack_seg(Wn0, Wg0, Wp0, 64, 3, f);           // 128x128
        else if (f < 24576) pack_seg(Wn1, Wg1, Wp1, 64, 3, f - 16384);   // 64x128
        else if (f < 28672) pack_seg(WnL, WgL, WpL, 32, 2, f - 24576);   // 64x64
        return;
    }
    if (blk >= SUBC) {
        int j = (blk - SUBC) * 256 + threadIdx.x;
        if (j < NIDX) mark[idx[j]] = 1;
        return;
    }
    __shared__ int hist[NB];
    int t = threadIdx.x;
    for (int b = t; b < NB; b += 256) hist[b] = 0;
    __syncthreads();
    for (int i = t; i < ECS; i += 256)
        atomicAdd(&hist[rows[blk * ECS + i] >> 6], 1);
    __syncthreads();
    for (int b = t; b < NB; b += 256) Bcnt4[blk * NB + b] = hist[b];
}

__global__ void bprefix_k(const int* __restrict__ Bcnt4, int* __restrict__ BcntT,
                          int* __restrict__ bTot) {
    int b = blockIdx.x * 256 + threadIdx.x;
    if (b >= NB) return;
    int run = 0;
    for (int sub = 0; sub < SUBC; sub++) {
        if ((sub & (SPC - 1)) == 0)
            BcntT[(sub / SPC) * NB + b] = run;   // coalesced read & write
        run += Bcnt4[sub * NB + b];
    }
    bTot[b] = run;
}

__global__ void bscan_k(const int* __restrict__ bTot, int* __restrict__ bBase) {
    __shared__ int s[256];
    int t = threadIdx.x;
    int v[7], loc = 0;
#pragma unroll
    for (int i = 0; i < 7; i++) {
        int ix = t * 7 + i;
        v[i] = loc;
        loc += (ix < NB) ? bTot[ix] : 0;
    }
    s[t] = loc;
    __syncthreads();
    for (int off = 1; off < 256; off <<= 1) {
        int a = (t >= off) ? s[t - off] : 0;
        __syncthreads();
        s[t] += a;
        __syncthreads();
    }
    int base = s[t] - loc;
#pragma unroll
    for (int i = 0; i < 7; i++) {
        int ix = t * 7 + i;
        if (ix < NB) bBase[ix] = base + v[i];
    }
    if (t == 255) bBase[NB] = NEDGES;
}

// ---------------------------------------------------------------------------
// bfinal+spmm0 FUSED: one block per bucket (64 rows, ~512 edges).
// Phase 1 (bfinal): LDS 64-bin hist + scan -> rowptr; scatter {col,val} into
//   final row-sorted cs.  ebuf entry: x = (row&63)<<20 | col, y = val bits.
// Phase 2 (spmm0): the block's sc[]/hist[] already hold the rowptr segment;
//   the cs segment just written is L2-hot (barrier drains vmcnt -> visible).
//   S0[row] = Hn0[row] + sum val*Hg0[col] for the bucket's 64 rows + BN stats.
// ---------------------------------------------------------------------------

__global__ __launch_bounds__(256) void bfinal_spmm0_k(
    const uint2* __restrict__ ebuf, const int* __restrict__ bBase,
    int* __restrict__ rowptr, int2* __restrict__ cs,
    const unsigned short* __restrict__ Hgb, unsigned short* __restrict__ S,
    float* __restrict__ stats, int n)
{
    __shared__ int hist[64], sc[64], cur[64];
    __shared__ float rs[16][HID], rq[16][HID];
    int b = blockIdx.x, t = threadIdx.x;
    int e0 = bBase[b], e1 = bBase[b + 1];
    int r0 = b << 6;
    if (t < 64) hist[t] = 0;
    __syncthreads();
    for (int i = e0 + t; i < e1; i += 256)
        atomicAdd(&hist[(ebuf[i].x >> 20) & 63], 1);
    __syncthreads();
    if (t == 0) {
        int run = e0;
        for (int j = 0; j < 64; j++) { sc[j] = run; run += hist[j]; }
    }
    __syncthreads();
    if (t < 64) {
        cur[t] = sc[t];
        int r = r0 + t;
        if (r < NNODES) rowptr[r] = sc[t];
    }
    if (b == NB - 1 && t == 0) rowptr[NNODES] = NEDGES;
    __syncthreads();
    for (int i = e0 + t; i < e1; i += 256) {
        uint2 v = ebuf[i];
        int p = atomicAdd(&cur[(v.x >> 20) & 63], 1);
        cs[p] = make_int2((int)(v.x & 0xFFFFF), (int)v.y);
    }
    __syncthreads();   // vmcnt drained before barrier -> cs visible block-wide

    // ---- spmm0 phase: 16 groups x 16 lanes, 4 consecutive rows per group ----
    const int lane = t & 15, g = t >> 4;
    const int c0 = lane * 4;
    float4 sum = make_float4(0.f, 0.f, 0.f, 0.f);
    float4 sq  = make_float4(0.f, 0.f, 0.f, 0.f);
#pragma unroll
    for (int rr = 0; rr < 4; rr++) {
        int lr = g * 4 + rr;
        int row = r0 + lr;
        if (row >= n) break;
        int le0 = sc[lr], le1 = sc[lr] + hist[lr];
        uint2 h = *(const uint2*)&S[(size_t)row * HID + c0];
        float4 a0 = make_float4(bf2f_lo(h.x), bf2f_hi(h.x), bf2f_lo(h.y), bf2f_hi(h.y));
        float4 a1 = make_float4(0.f, 0.f, 0.f, 0.f), a2 = a1, a3 = a1;
        int e = le0;
        for (; e + 3 < le1; e += 4) {
            int2 p0 = cs[e], p1 = cs[e + 1], p2 = cs[e + 2], p3 = cs[e + 3];
            float v0 = __int_as_float(p0.y), v1 = __int_as_float(p1.y);
            float v2 = __int_as_float(p2.y), v3 = __int_as_float(p3.y);
            uint2 h0 = *(const uint2*)&Hgb[(size_t)p0.x * HID + c0];
            uint2 h1 = *(const uint2*)&Hgb[(size_t)p1.x * HID + c0];
            uint2 h2 = *(const uint2*)&Hgb[(size_t)p2.x * HID + c0];
            uint2 h3 = *(const uint2*)&Hgb[(size_t)p3.x * HID + c0];
            a0.x += v0 * bf2f_lo(h0.x); a0.y += v0 * bf2f_hi(h0.x);
            a0.z += v0 * bf2f_lo(h0.y); a0.w += v0 * bf2f_hi(h0.y);
            a1.x += v1 * bf2f_lo(h1.x); a1.y += v1 * bf2f_hi(h1.x);
            a1.z += v1 * bf2f_lo(h1.y); a1.w += v1 * bf2f_hi(h1.y);
            a2.x += v2 * bf2f_lo(h2.x); a2.y += v2 * bf2f_hi(h2.x);
            a2.z += v2 * bf2f_lo(h2.y); a2.w += v2 * bf2f_hi(h2.y);
            a3.x += v3 * bf2f_lo(h3.x); a3.y += v3 * bf2f_hi(h3.x);
            a3.z += v3 * bf2f_lo(h3.y); a3.w += v3 * bf2f_hi(h3.y);
        }
        for (; e < le1; e++) {
            int2 p = cs[e];
            float v = __int_as_float(p.y);
            uint2 hh = *(const uint2*)&Hgb[(size_t)p.x * HID + c0];
            a0.x += v * bf2f_lo(hh.x); a0.y += v * bf2f_hi(hh.x);
            a0.z += v * bf2f_lo(hh.y); a0.w += v * bf2f_hi(hh.y);
        }
        float4 acc = make_float4(a0.x + a1.x + a2.x + a3.x, a0.y + a1.y + a2.y + a3.y,
                                 a0.z + a1.z + a2.z + a3.z, a0.w + a1.w + a2.w + a3.w);
        uint2 o;
        o.x = (unsigned)f2bf(acc.x) | ((unsigned)f2bf(acc.y) << 16);
        o.y = (unsigned)f2bf(acc.z) | ((unsigned)f2bf(acc.w) << 16);
        *(uint2*)&S[(size_t)row * HID + c0] = o;
        sum.x += acc.x; sum.y += acc.y; sum.z += acc.z; sum.w += acc.w;
        sq.x += acc.x * acc.x; sq.y += acc.y * acc.y;
        sq.z += acc.z * acc.z; sq.w += acc.w * acc.w;
    }

    *(float4*)&rs[g][c0] = sum;
    *(float4*)&rq[g][c0] = sq;
    __syncthreads();
    if (t < HID) {
        float a = 0.f, bb = 0.f;
        for (int w = 0; w < 16; w++) { a += rs[w][t]; bb += rq[w][t]; }
        int stripe = b & 7;
        atomicAdd(&stats[stripe * 128 + t], a);
        atomicAdd(&stats[stripe * 128 + HID + t], bb);
    }
}

// ---------------------------------------------------------------------------
// MFMA dual-GEMM body. [Hn | Hg] = act(X) @ [Wn | Wg] (+ per-col biases);
// Hg always bf16 out; Hn bf16 (HNBF) or fp32. X fp32 or bf16 (XBF).
// AFF: BN scale/shift recomputed in-block from striped sums.
// Epilogue: bf16 outputs staged through LDS (reusing Xs) -> coalesced uint4.
// ---------------------------------------------------------------------------

template <int K, int HOUT, bool AFF, bool XBF, bool HNBF>
__device__ void gemm_body(const void* __restrict__ Xv, const unsigned short* __restrict__ Wp,
                          const float* __restrict__ bnA, const float* __restrict__ bnB,
                          const float* __restrict__ bgA,
                          const float* __restrict__ sums, const float* __restrict__ gamma,
                          const float* __restrict__ beta,
                          float* __restrict__ Hnf, unsigned short* __restrict__ Hnb,
                          unsigned short* __restrict__ Hgb, int n, int blk)
{
    constexpr int NT = 2 * HOUT / 16, NKB = K / 32;
    constexpr int RS = K + 8;                       // staging row stride (shorts)
    constexpr int OC = HNBF ? 2 * HOUT : HOUT;      // cols staged through LDS in epilogue
    constexpr int RSE = OC + 8;                     // epilogue row stride (shorts, 16B mult)
    constexpr int XSZ = (RS > RSE) ? RS : RSE;
    __shared__ unsigned short Xs[64 * XSZ];
    __shared__ float sSc[64], sSh[64];

    const int row0 = blk * 64;
    const int t = threadIdx.x;

    if (AFF) {               // in-block BN finalize: 1KB of reads, once per block
        if (t < 64) {
            float sum = 0.f, sq = 0.f;
#pragma unroll
            for (int s = 0; s < 8; s++) { sum += sums[s * 128 + t]; sq += sums[s * 128 + 64 + t]; }
            float m = sum / (float)NNODES;
            float var = sq / (float)NNODES - m * m;
            float sc = gamma[t] * rsqrtf(var + BN_EPS);
            sSc[t] = sc; sSh[t] = beta[t] - m * sc;
        }
        __syncthreads();
    }

    // Stage 64 x K -> bf16 LDS. Loads batched first (row-clamped, unconditional),
    // then convert (+affine+relu) and ds_write.
    constexpr int SIT = K / 32;      // staging iterations per thread (256 thr)
    if constexpr (XBF) {
        uint4 u[SIT];
#pragma unroll
        for (int it = 0; it < SIT; it++) {
            int li = it * 256 + t;
            int rr = row0 + li / (K / 8);
            int k8 = (li % (K / 8)) * 8;
            int rc = rr < n ? rr : n - 1;
            u[it] = *(const uint4*)((const unsigned short*)Xv + (size_t)rc * K + k8);
        }
#pragma unroll
        for (int it = 0; it < SIT; it++) {
            int li = it * 256 + t;
            int r  = li / (K / 8);
            int k8 = (li % (K / 8)) * 8;
            float v[8];
            v[0] = bf2f_lo(u[it].x); v[1] = bf2f_hi(u[it].x);
            v[2] = bf2f_lo(u[it].y); v[3] = bf2f_hi(u[it].y);
            v[4] = bf2f_lo(u[it].z); v[5] = bf2f_hi(u[it].z);
            v[6] = bf2f_lo(u[it].w); v[7] = bf2f_hi(u[it].w);
            if (AFF) {
#pragma unroll
                for (int i = 0; i < 8; i++) v[i] = fmaxf(v[i] * sSc[k8 + i] + sSh[k8 + i], 0.f);
            }
            uint4 o;
            o.x = (unsigned)f2bf(v[0]) | ((unsigned)f2bf(v[1]) << 16);
            o.y = (unsigned)f2bf(v[2]) | ((unsigned)f2bf(v[3]) << 16);
            o.z = (unsigned)f2bf(v[4]) | ((unsigned)f2bf(v[5]) << 16);
            o.w = (unsigned)f2bf(v[6]) | ((unsigned)f2bf(v[7]) << 16);
            *(uint4*)&Xs[r * RS + k8] = o;
        }
    } else {
        const float* Xf = (const float*)Xv;
        float4 a[SIT], b[SIT];
#pragma unroll
        for (int it = 0; it < SIT; it++) {
            int li = it * 256 + t;
            int rr = row0 + li / (K / 8);
            int k8 = (li % (K / 8)) * 8;
            int rc = rr < n ? rr : n - 1;
            a[it] = *(const float4*)&Xf[(size_t)rc * K + k8];
            b[it] = *(const float4*)&Xf[(size_t)rc * K + k8 + 4];
        }
#pragma unroll
        for (int it = 0; it < SIT; it++) {
            int li = it * 256 + t;
            int r  = li / (K / 8);
            int k8 = (li % (K / 8)) * 8;
            float v[8] = { a[it].x, a[it].y, a[it].z, a[it].w,
                           b[it].x, b[it].y, b[it].z, b[it].w };
            if (AFF) {
#pragma unroll
                for (int i = 0; i < 8; i++) v[i] = fmaxf(v[i] * sSc[k8 + i] + sSh[k8 + i], 0.f);
            }
            uint4 o;
            o.x = (unsigned)f2bf(v[0]) | ((unsigned)f2bf(v[1]) << 16);
            o.y = (unsigned)f2bf(v[2]) | ((unsigned)f2bf(v[3]) << 16);
            o.z = (unsigned)f2bf(v[4]) | ((unsigned)f2bf(v[5]) << 16);
            o.w = (unsigned)f2bf(v[6]) | ((unsigned)f2bf(v[7]) << 16);
            *(uint4*)&Xs[r * RS + k8] = o;
        }
    }
    __syncthreads();

    const int wave = t >> 6, lane = t & 63;
    const int q = lane >> 4, mrow = lane & 15;

    f32x4 acc[NT];
#pragma unroll
    for (int i = 0; i < NT; i++) acc[i] = (f32x4){0.f, 0.f, 0.f, 0.f};

    const short8* wp8 = (const short8*)Wp;
#pragma unroll
    for (int kb = 0; kb < NKB; kb++) {
        short8 va = *(const short8*)&Xs[(wave * 16 + mrow) * RS + kb * 32 + q * 8];
#pragma unroll
        for (int tt = 0; tt < NT; tt++) {
            short8 vb = wp8[(kb * NT + tt) * 64 + lane];   // coalesced dwordx4
            acc[tt] = __builtin_amdgcn_mfma_f32_16x16x32_bf16(va, vb, acc[tt], 0, 0, 0);
        }
    }

    // Epilogue. C/D: col = lane&15 (tile tt), row = q*4 + reg.
    // bf16 outputs -> LDS (reuse Xs) -> coalesced uint4 stores.
    __syncthreads();          // all waves done reading staging Xs
#pragma unroll
    for (int tt = 0; tt < NT; tt++) {
        int nglob = tt * 16 + mrow;
        bool nside = (nglob < HOUT);
        int c = nside ? nglob : (nglob - HOUT);
        float bias = 0.f;
        if (nside) {
            if (bnA) bias += bnA[c];
            if (bnB) bias += bnB[c];
        } else if (bgA) {
            bias += bgA[c];
        }
        if (HNBF || !nside) {
            int cc = HNBF ? nglob : c;
#pragma unroll
            for (int r = 0; r < 4; r++)
                Xs[(wave * 16 + q * 4 + r) * RSE + cc] = f2bf(acc[tt][r] + bias);
        } else {
            // fp32 Hn half (last layer only): direct stores
#pragma unroll
            for (int r = 0; r < 4; r++) {
                int rr = row0 + wave * 16 + q * 4 + r;
                if (rr < n) Hnf[(size_t)rr * HOUT + c] = acc[tt][r] + bias;
            }
        }
    }
    __syncthreads();
    constexpr int J = OC / 8;                 // uint4 per row
#pragma unroll
    for (int u2 = 0; u2 < (64 * J) / 256; u2++) {
        int li = u2 * 256 + t;
        int r = li / J, j = li % J;
        int rr = row0 + r;
        if (rr < n) {
            uint4 v = *(const uint4*)&Xs[r * RSE + j * 8];
            int c8 = j * 8;
            if (HNBF && c8 < HOUT)
                *(uint4*)&Hnb[(size_t)rr * HOUT + c8] = v;
            else
                *(uint4*)&Hgb[(size_t)rr * HOUT + (HNBF ? c8 - HOUT : c8)] = v;
        }
    }
}

// K_C: blocks [0,NCHK*PF): bucket-partition. Each chunk is handled by PF
//      blocks; sibling blocks are mapped chunk = i % NCHK, pf = i / NCHK so
//      all PF siblings of a chunk share i%8 (same XCD under round-robin
//      dispatch) -> the chunk's rows/cols/vals are fetched once per XCD L2.
//      rows+cols+vals streamed as coalesced int4/float4.
//      blocks [NCHK*PF,..): layer-0 dual GEMM (co-scheduled, independent).
__global__ __launch_bounds__(256) void part_gemm0_k(
    const int* __restrict__ rows, const int* __restrict__ cols,
    const float* __restrict__ vals, const int* __restrict__ BcntT,
    const int* __restrict__ bBase, uint2* __restrict__ ebuf,
    const float* __restrict__ X, const unsigned short* __restrict__ Wp0,
    const float* __restrict__ bn0, const float* __restrict__ ab0, const float* __restrict__ bg0,
    unsigned short* __restrict__ Hn0b, unsigned short* __restrict__ Hgb, int n)
{
    if ((int)blockIdx.x < NCHK * PF) {
        __shared__ int cur[NBF];
        int t = threadIdx.x;
        int blk = blockIdx.x % NCHK;          // sibling co-location: i%8 == blk%8
        int pf  = blockIdx.x / NCHK;
        int b0 = pf * NBF, b1 = (pf == PF - 1) ? NB : (b0 + NBF);
        for (int b = b0 + t; b < b1; b += 256)
            cur[b - b0] = bBase[b] + BcntT[blk * NB + b];
        __syncthreads();
        constexpr int EC4 = EC / 4;           // 3125 int4 reads per chunk stream
        const int*   rbase = rows + blk * EC;
        const int*   cbase = cols + blk * EC;
        const float* vbase = vals + blk * EC;
        for (int i4 = t; i4 < EC4; i4 += 256) {
            int4   r4 = *(const int4*)&rbase[i4 * 4];
            int4   c4 = *(const int4*)&cbase[i4 * 4];
            float4 v4 = *(const float4*)&vbase[i4 * 4];
#pragma unroll
            for (int j = 0; j < 4; j++) {
                int r = (&r4.x)[j];
                int b = r >> 6;
                if (b >= b0 && b < b1) {
                    int p = atomicAdd(&cur[b - b0], 1);    // LDS atomic
                    ebuf[p] = make_uint2(((unsigned)(r & 63) << 20) | (unsigned)(&c4.x)[j],
                                         (unsigned)__float_as_int((&v4.x)[j]));
                }
            }
        }
    } else {
        gemm_body<DIN, HID, false, false, true>(X, Wp0, bn0, ab0, bg0,
            nullptr, nullptr, nullptr, nullptr, Hn0b, Hgb, n, blockIdx.x - NCHK * PF);
    }
}

template <int K, int HOUT, bool AFF, bool XBF, bool HNBF>
__global__ __launch_bounds__(256) void gemm_k(
    const void* __restrict__ X, const unsigned short* __restrict__ Wp,
    const float* __restrict__ bnA, const float* __restrict__ bnB, const float* __restrict__ bgA,
    const float* __restrict__ sums, const float* __restrict__ gamma, const float* __restrict__ beta,
    float* __restrict__ Hnf, unsigned short* __restrict__ Hnb, unsigned short* __restrict__ Hgb, int n)
{
    gemm_body<K, HOUT, AFF, XBF, HNBF>(X, Wp, bnA, bnB, bgA, sums, gamma, beta,
                                       Hnf, Hnb, Hgb, n, blockIdx.x);
}

// ---------------------------------------------------------------------------
// SpMM v2 (block-local CSR staging): each block owns 64 CONSECUTIVE rows;
// stages rowptr[65] + the block's whole edge segment (~512 edges) into LDS
// with coalesced loads; groups then read edges from LDS (broadcast,
// conflict-free) and issue only the Hgb gathers. Overflow (>1024 edges)
// falls back to direct global reads per row.
// ---------------------------------------------------------------------------

template <int HH, bool STATS, bool SBF, bool MARKED>
__global__ __launch_bounds__(256) void spmm_k(
    const int* __restrict__ rowptr, const int2* __restrict__ cs,
    const unsigned short* __restrict__ Hgb, void* __restrict__ Sv,
    float* __restrict__ stats, const int* __restrict__ mark, int n)
{
    constexpr int L   = HH / 4;     // lanes per group (16 or 8)
    constexpr int GP  = 256 / L;    // groups per block (16 or 32)
    constexpr int RPB = 64;         // rows per block (consecutive)
    constexpr int RPG = RPB / GP;   // rows per group (4 or 2)
    constexpr int ECAP = 1024;      // staged-edge capacity (8KB)
    __shared__ int2 es[ECAP];
    __shared__ int  rp[RPB + 1];

    const int t = threadIdx.x;
    const int R0 = blockIdx.x * RPB;
    if (t <= RPB) rp[t] = rowptr[min(R0 + t, n)];
    __syncthreads();
    const int e0b  = rp[0];
    const int scnt = min(rp[RPB] - e0b, ECAP);
    for (int i = t; i < scnt; i += 256) es[i] = cs[e0b + i];   // coalesced 8B
    __syncthreads();

    const int lane = t % L;
    const int g    = t / L;
    const int c0   = lane * 4;

    float4 sum = make_float4(0.f, 0.f, 0.f, 0.f);
    float4 sq  = make_float4(0.f, 0.f, 0.f, 0.f);

#define SPMM_ROW(FETCH)                                                            \
    {                                                                              \
        int e = le0;                                                               \
        for (; e + 3 < le1; e += 4) {                                              \
            int2 p0 = FETCH(e), p1 = FETCH(e + 1), p2 = FETCH(e + 2), p3 = FETCH(e + 3); \
            float v0 = __int_as_float(p0.y), v1 = __int_as_float(p1.y);            \
            float v2 = __int_as_float(p2.y), v3 = __int_as_float(p3.y);            \
            uint2 h0 = *(const uint2*)&Hgb[(size_t)p0.x * HH + c0];                \
            uint2 h1 = *(const uint2*)&Hgb[(size_t)p1.x * HH + c0];                \
            uint2 h2 = *(const uint2*)&Hgb[(size_t)p2.x * HH + c0];                \
            uint2 h3 = *(const uint2*)&Hgb[(size_t)p3.x * HH + c0];                \
            a0.x += v0 * bf2f_lo(h0.x); a0.y += v0 * bf2f_hi(h0.x);                \
            a0.z += v0 * bf2f_lo(h0.y); a0.w += v0 * bf2f_hi(h0.y);                \
            a1.x += v1 * bf2f_lo(h1.x); a1.y += v1 * bf2f_hi(h1.x);                \
            a1.z += v1 * bf2f_lo(h1.y); a1.w += v1 * bf2f_hi(h1.y);                \
            a2.x += v2 * bf2f_lo(h2.x); a2.y += v2 * bf2f_hi(h2.x);                \
            a2.z += v2 * bf2f_lo(h2.y); a2.w += v2 * bf2f_hi(h2.y);                \
            a3.x += v3 * bf2f_lo(h3.x); a3.y += v3 * bf2f_hi(h3.x);                \
            a3.z += v3 * bf2f_lo(h3.y); a3.w += v3 * bf2f_hi(h3.y);                \
        }                                                                          \
        for (; e < le1; e++) {                                                     \
            int2 p = FETCH(e);                                                     \
            float v = __int_as_float(p.y);                                         \
            uint2 h = *(const uint2*)&Hgb[(size_t)p.x * HH + c0];                  \
            a0.x += v * bf2f_lo(h.x); a0.y += v * bf2f_hi(h.x);                    \
            a0.z += v * bf2f_lo(h.y); a0.w += v * bf2f_hi(h.y);                    \
        }                                                                          \
    }
#define F_LDS(i) es[(i)]
#define F_GLB(i) cs[e0b + (i)]

#pragma unroll
    for (int rr = 0; rr < RPG; rr++) {
        int row = R0 + g * RPG + rr;
        if (row >= n) break;
        if (MARKED && !mark[row]) continue;
        int le0 = rp[g * RPG + rr] - e0b;
        int le1 = rp[g * RPG + rr + 1] - e0b;
        float4 a0, a1, a2, a3;
        if (SBF) {
            uint2 h = *(const uint2*)((const unsigned short*)Sv + (size_t)row * HH + c0);
            a0 = make_float4(bf2f_lo(h.x), bf2f_hi(h.x), bf2f_lo(h.y), bf2f_hi(h.y));
        } else {
            a0 = *(const float4*)((const float*)Sv + (size_t)row * HH + c0);
        }
        a1 = a2 = a3 = make_float4(0.f, 0.f, 0.f, 0.f);
        if (le1 <= scnt) SPMM_ROW(F_LDS) else SPMM_ROW(F_GLB);
        float4 acc = make_float4(a0.x + a1.x + a2.x + a3.x, a0.y + a1.y + a2.y + a3.y,
                                 a0.z + a1.z + a2.z + a3.z, a0.w + a1.w + a2.w + a3.w);
        if (SBF) {
            uint2 o;
            o.x = (unsigned)f2bf(acc.x) | ((unsigned)f2bf(acc.y) << 16);
            o.y = (unsigned)f2bf(acc.z) | ((unsigned)f2bf(acc.w) << 16);
            *(uint2*)((unsigned short*)Sv + (size_t)row * HH + c0) = o;
        } else {
            *(float4*)((float*)Sv + (size_t)row * HH + c0) = acc;
        }
        if (STATS) {
            sum.x += acc.x; sum.y += acc.y; sum.z += acc.z; sum.w += acc.w;
            sq.x += acc.x * acc.x; sq.y += acc.y * acc.y;
            sq.z += acc.z * acc.z; sq.w += acc.w * acc.w;
        }
    }
#undef SPMM_ROW
#undef F_LDS
#undef F_GLB

    if constexpr (STATS) {
        __shared__ float rs[GP][HH];
        __shared__ float rq[GP][HH];
        *(float4*)&rs[g][c0] = sum;
        *(float4*)&rq[g][c0] = sq;
        __syncthreads();
        if (threadIdx.x < HH) {
            float a = 0.f, b = 0.f;
            for (int w = 0; w < GP; w++) { a += rs[w][threadIdx.x]; b += rq[w][threadIdx.x]; }
            int stripe = blockIdx.x & 7;
            atomicAdd(&stats[stripe * 128 + threadIdx.x], a);
            atomicAdd(&stats[stripe * 128 + HH + threadIdx.x], b);
        }
    }
}

__global__ void gather_k(const float* __restrict__ S, const int* __restrict__ idx,
                         float* __restrict__ out, int total4) {
    int j = blockIdx.x * 256 + threadIdx.x;
    if (j < total4) {
        int r = j / (EMB / 4), c4 = (j % (EMB / 4)) * 4;
        *(float4*)&out[(size_t)j * 4] = *(const float4*)&S[(size_t)idx[r] * EMB + c4];
    }
}

// ---------------------------------------------------------------------------

extern "C" void kernel_launch(void* const* d_in, const int* in_sizes, int n_in,
                              void* d_out, int out_size, void* d_ws, size_t ws_size,
                              hipStream_t stream) {
    const float* features = (const float*)d_in[0];
    const int*   rows     = (const int*)d_in[1];
    const int*   cols     = (const int*)d_in[2];
    const float* vals     = (const float*)d_in[3];
    const int*   idx      = (const int*)d_in[4];
    const float* Wn0 = (const float*)d_in[5];
    const float* bn0 = (const float*)d_in[6];
    const float* Wg0 = (const float*)d_in[7];
    const float* bg0 = (const float*)d_in[8];
    const float* ab0 = (const float*)d_in[9];
    const float* g0  = (const float*)d_in[10];
    const float* b0  = (const float*)d_in[11];
    const float* Wn1 = (const float*)d_in[12];
    const float* Wg1 = (const float*)d_in[13];
    const float* ab1 = (const float*)d_in[14];
    const float* g1  = (const float*)d_in[15];
    const float* b1  = (const float*)d_in[16];
    const float* WnL = (const float*)d_in[17];
    const float* WgL = (const float*)d_in[18];
    const float* abL = (const float*)d_in[19];
    float* out = (float*)d_out;

    // Workspace layout (~70 MB), 16B-aligned sub-buffers.
    float*          HnLf = (float*)d_ws;                        // N x EMB fp32 (HnL/SL)
    unsigned short* nA   = (unsigned short*)(HnLf + (size_t)NNODES * EMB); // Hn0/S0 bf16
    unsigned short* nB   = nA + (size_t)NNODES * HID;           // Hn1/S1 bf16
    unsigned short* Hgb  = nB + (size_t)NNODES * HID;           // Hg (all layers) bf16
    uint2* ebuf  = (uint2*)(Hgb + (size_t)NNODES * HID);        // E x 8B (packed)
    int2*  cs    = (int2*)(ebuf + NEDGES);                      // E (row-sorted payload)
    int*   rowptr = (int*)(cs + NEDGES);                        // N+4
    int*   Bcnt4 = rowptr + (NNODES + 4);                       // SUBC x NB
    int*   BcntT = Bcnt4 + SUBC * NB;                           // NCHK x NB
    int*   bTot  = BcntT + NCHK * NB;                           // NB (pad 1568)
    int*   bBase = bTot + 1568;                                 // NB+1 (pad 1568)
    unsigned short* Wp0 = (unsigned short*)(bBase + 1568);      // 16384
    unsigned short* Wp1 = Wp0 + 16384;                          // 8192
    unsigned short* WpL = Wp1 + 8192;                           // 4096
    // ---- single zeroed region: stats | mark ----
    float* stats = (float*)(WpL + 4096);                        // 2304
    int*   mark  = (int*)(stats + 2304);                        // N
    float* sums0 = stats;
    float* sums1 = stats + 1024;
    size_t zbytes = 2304 * 4 + (size_t)NNODES * 4;

    hipMemsetAsync(stats, 0, zbytes, stream);

    const int GBm = (NNODES + 63) / 64;     // 1563
    const int MB  = (NIDX + 255) / 256;     // 196

    // K1: bucket histogram + mark + W pre-pack (independent branches).
    histpack_k<<<SUBC + MB + 112, 256, 0, stream>>>(
        rows, Bcnt4, idx, mark, Wn0, Wg0, Wn1, Wg1, WnL, WgL, Wp0, Wp1, WpL, MB);
    bprefix_k<<<7, 256, 0, stream>>>(Bcnt4, BcntT, bTot);
    bscan_k<<<1, 256, 0, stream>>>(bTot, bBase);
    part_gemm0_k<<<NCHK * PF + GBm, 256, 0, stream>>>(rows, cols, vals, BcntT, bBase, ebuf,
                                                      features, Wp0, bn0, ab0, bg0,
                                                      nA, Hgb, NNODES);
    // FUSED: bucket sort -> rowptr/cs AND layer-0 aggregate S0 = Hn0 + A@Hg0
    bfinal_spmm0_k<<<NB, 256, 0, stream>>>(ebuf, bBase, rowptr, cs, Hgb, nA, sums0, NNODES);

    // Layer 1: BN finalize folded into gemm; S1 = Hn1 + ab1 + A@Hg1
    gemm_k<HID, HID, true, true, true><<<GBm, 256, 0, stream>>>(
        nA, Wp1, ab1, nullptr, nullptr, sums0, g0, b0, nullptr, nB, Hgb, NNODES);
    spmm_k<HID, true, true, false><<<GBm, 256, 0, stream>>>(rowptr, cs, Hgb, nB, sums1, nullptr, NNODES);

    // Last layer: HnL fp32; aggregate only rows referenced by idx.
    gemm_k<HID, EMB, true, true, false><<<GBm, 256, 0, stream>>>(
        nB, WpL, abL, nullptr, nullptr, sums1, g1, b1, HnLf, nullptr, Hgb, NNODES);
    spmm_k<EMB, false, false, true><<<GBm, 256, 0, stream>>>(rowptr, cs, Hgb, HnLf, nullptr, mark, NNODES);

    gather_k<<<(NIDX * EMB / 4 + 255) / 256, 256, 0, stream>>>(HnLf, idx, out, NIDX * EMB / 4);
}

// Round 9
// 257.963 us; speedup vs baseline: 1.2614x; 1.0700x over previous
//
#include <hip/hip_runtime.h>

// Problem constants (fixed by the reference).
#define NNODES 100000
#define NEDGES 800000
#define DIN    128
#define HID    64
#define EMB    32
#define NIDX   50000
#define BN_EPS 1e-5f

#define NCHK 64                   // partition chunks (64 -> ~8-edge runs per bucket, 64B)
#define EC   (NEDGES / NCHK)      // 12500 edges per chunk
#define NB   ((NNODES + 63) / 64) // 1563 row-buckets of 64 rows
#define PF   16                   // bucket fractions per chunk (scatter parallelism)
#define NBF  ((NB + PF - 1) / PF) // 98 buckets per fraction

typedef __attribute__((ext_vector_type(8))) short short8;   // 8 bf16 = 4 VGPR
typedef __attribute__((ext_vector_type(4))) float f32x4;    // MFMA C/D

__device__ inline unsigned short f2bf(float f) {            // RNE, matches HW
    unsigned u = __float_as_uint(f);
    unsigned r = u + 0x7FFFu + ((u >> 16) & 1u);
    return (unsigned short)(r >> 16);
}
__device__ inline float bf2f_lo(unsigned u) { return __uint_as_float(u << 16); }
__device__ inline float bf2f_hi(unsigned u) { return __uint_as_float(u & 0xffff0000u); }

// ---------------------------------------------------------------------------
// W pre-pack: fp32 [Wn|Wg] -> bf16 B-fragment-major (GEMM B-loads coalesced).
// ---------------------------------------------------------------------------

__device__ inline void pack_seg(const float* __restrict__ Wn, const float* __restrict__ Wg,
                                unsigned short* __restrict__ Wp, int HOUT, int l2nt, int f) {
    int j = f & 7, lane = (f >> 3) & 63, g = f >> 9;
    int tt = g & ((1 << l2nt) - 1), kb = g >> l2nt;
    int k = kb * 32 + ((lane >> 4) * 8) + j;
    int nn = tt * 16 + (lane & 15);
    float v = (nn < HOUT) ? Wn[k * HOUT + nn] : Wg[k * HOUT + (nn - HOUT)];
    Wp[f] = f2bf(v);
}

// ---------------------------------------------------------------------------
// K1: blocks [0,NCHK): per-chunk bucket histogram -> Bcnt4[chunk][b]
//     + bucket totals bTot[b] via global atomics (breaks prefix/scan dep).
//     blocks [NCHK,NCHK+MB): mark[idx[j]] = 1
//     blocks [NCHK+MB,..): W pre-pack (all 3 layers)  -- all independent.
// ---------------------------------------------------------------------------

__global__ __launch_bounds__(256) void histpack_k(
    const int* __restrict__ rows, int* __restrict__ Bcnt4, int* __restrict__ bTot,
    const int* __restrict__ idx, int* __restrict__ mark,
    const float* Wn0, const float* Wg0, const float* Wn1,
    const float* Wg1, const float* WnL, const float* WgL,
    unsigned short* Wp0, unsigned short* Wp1, unsigned short* WpL, int MB)
{
    int blk = blockIdx.x;
    int t = threadIdx.x;
    if (blk >= NCHK + MB) {
        int f = (blk - NCHK - MB) * 256 + t;
        if (f < 16384)      pack_seg(Wn0, Wg0, Wp0, 64, 3, f);           // 128x128
        else if (f < 24576) pack_seg(Wn1, Wg1, Wp1, 64, 3, f - 16384);   // 64x128
        else if (f < 28672) pack_seg(WnL, WgL, WpL, 32, 2, f - 24576);   // 64x64
        return;
    }
    if (blk >= NCHK) {
        int j = (blk - NCHK) * 256 + t;
        if (j < NIDX) mark[idx[j]] = 1;
        return;
    }
    __shared__ int hist[NB];
    for (int b = t; b < NB; b += 256) hist[b] = 0;
    __syncthreads();
    const int* rbase = rows + blk * EC;
    for (int i4 = t; i4 < EC / 4; i4 += 256) {           // 3125 int4 reads
        int4 r4 = *(const int4*)&rbase[i4 * 4];
        atomicAdd(&hist[r4.x >> 6], 1);
        atomicAdd(&hist[r4.y >> 6], 1);
        atomicAdd(&hist[r4.z >> 6], 1);
        atomicAdd(&hist[r4.w >> 6], 1);
    }
    __syncthreads();
    for (int b = t; b < NB; b += 256) {
        int h = hist[b];
        Bcnt4[blk * NB + b] = h;
        if (h) atomicAdd(&bTot[b], h);                   // device-scope
    }
}

// scan_k: ONE dispatch, two independent jobs (both depend only on histpack):
//   blocks 0..6: per-bucket prefix over chunks -> BcntT[chunk][b]
//   block 7:     exclusive scan of bTot -> bBase (bucket bases)
__global__ __launch_bounds__(256) void scan_k(
    const int* __restrict__ Bcnt4, int* __restrict__ BcntT,
    const int* __restrict__ bTot, int* __restrict__ bBase)
{
    int t = threadIdx.x;
    if (blockIdx.x < 7) {
        int b = blockIdx.x * 256 + t;
        if (b >= NB) return;
        int run = 0;
        for (int c = 0; c < NCHK; c++) {
            BcntT[c * NB + b] = run;     // coalesced read & write
            run += Bcnt4[c * NB + b];
        }
        return;
    }
    __shared__ int s[256];
    int v[7], loc = 0;
#pragma unroll
    for (int i = 0; i < 7; i++) {
        int ix = t * 7 + i;
        v[i] = loc;
        loc += (ix < NB) ? bTot[ix] : 0;
    }
    s[t] = loc;
    __syncthreads();
    for (int off = 1; off < 256; off <<= 1) {
        int a = (t >= off) ? s[t - off] : 0;
        __syncthreads();
        s[t] += a;
        __syncthreads();
    }
    int base = s[t] - loc;
#pragma unroll
    for (int i = 0; i < 7; i++) {
        int ix = t * 7 + i;
        if (ix < NB) bBase[ix] = base + v[i];
    }
    if (t == 255) bBase[NB] = NEDGES;
}

// ---------------------------------------------------------------------------
// bfinal+spmm0 FUSED: one block per bucket (64 rows, ~512 edges).
// Phase 1 (bfinal): LDS 64-bin hist + scan -> rowptr; scatter {col,val} into
//   final row-sorted cs.  ebuf entry: x = (row&63)<<20 | col, y = val bits.
// Phase 2 (spmm0): the block's sc[]/hist[] already hold the rowptr segment;
//   the cs segment just written is L2-hot (barrier drains vmcnt -> visible).
//   S0[row] = Hn0[row] + sum val*Hg0[col] for the bucket's 64 rows + BN stats.
// ---------------------------------------------------------------------------

__global__ __launch_bounds__(256) void bfinal_spmm0_k(
    const uint2* __restrict__ ebuf, const int* __restrict__ bBase,
    int* __restrict__ rowptr, int2* __restrict__ cs,
    const unsigned short* __restrict__ Hgb, unsigned short* __restrict__ S,
    float* __restrict__ stats, int n)
{
    __shared__ int hist[64], sc[64], cur[64];
    __shared__ float rs[16][HID], rq[16][HID];
    int b = blockIdx.x, t = threadIdx.x;
    int e0 = bBase[b], e1 = bBase[b + 1];
    int r0 = b << 6;
    if (t < 64) hist[t] = 0;
    __syncthreads();
    for (int i = e0 + t; i < e1; i += 256)
        atomicAdd(&hist[(ebuf[i].x >> 20) & 63], 1);
    __syncthreads();
    if (t == 0) {
        int run = e0;
        for (int j = 0; j < 64; j++) { sc[j] = run; run += hist[j]; }
    }
    __syncthreads();
    if (t < 64) {
        cur[t] = sc[t];
        int r = r0 + t;
        if (r < NNODES) rowptr[r] = sc[t];
    }
    if (b == NB - 1 && t == 0) rowptr[NNODES] = NEDGES;
    __syncthreads();
    for (int i = e0 + t; i < e1; i += 256) {
        uint2 v = ebuf[i];
        int p = atomicAdd(&cur[(v.x >> 20) & 63], 1);
        cs[p] = make_int2((int)(v.x & 0xFFFFF), (int)v.y);
    }
    __syncthreads();   // vmcnt drained before barrier -> cs visible block-wide

    // ---- spmm0 phase: 16 groups x 16 lanes, 4 consecutive rows per group ----
    const int lane = t & 15, g = t >> 4;
    const int c0 = lane * 4;
    float4 sum = make_float4(0.f, 0.f, 0.f, 0.f);
    float4 sq  = make_float4(0.f, 0.f, 0.f, 0.f);
#pragma unroll
    for (int rr = 0; rr < 4; rr++) {
        int lr = g * 4 + rr;
        int row = r0 + lr;
        if (row >= n) break;
        int le0 = sc[lr], le1 = sc[lr] + hist[lr];
        uint2 h = *(const uint2*)&S[(size_t)row * HID + c0];
        float4 a0 = make_float4(bf2f_lo(h.x), bf2f_hi(h.x), bf2f_lo(h.y), bf2f_hi(h.y));
        float4 a1 = make_float4(0.f, 0.f, 0.f, 0.f), a2 = a1, a3 = a1;
        int e = le0;
        for (; e + 3 < le1; e += 4) {
            int2 p0 = cs[e], p1 = cs[e + 1], p2 = cs[e + 2], p3 = cs[e + 3];
            float v0 = __int_as_float(p0.y), v1 = __int_as_float(p1.y);
            float v2 = __int_as_float(p2.y), v3 = __int_as_float(p3.y);
            uint2 h0 = *(const uint2*)&Hgb[(size_t)p0.x * HID + c0];
            uint2 h1 = *(const uint2*)&Hgb[(size_t)p1.x * HID + c0];
            uint2 h2 = *(const uint2*)&Hgb[(size_t)p2.x * HID + c0];
            uint2 h3 = *(const uint2*)&Hgb[(size_t)p3.x * HID + c0];
            a0.x += v0 * bf2f_lo(h0.x); a0.y += v0 * bf2f_hi(h0.x);
            a0.z += v0 * bf2f_lo(h0.y); a0.w += v0 * bf2f_hi(h0.y);
            a1.x += v1 * bf2f_lo(h1.x); a1.y += v1 * bf2f_hi(h1.x);
            a1.z += v1 * bf2f_lo(h1.y); a1.w += v1 * bf2f_hi(h1.y);
            a2.x += v2 * bf2f_lo(h2.x); a2.y += v2 * bf2f_hi(h2.x);
            a2.z += v2 * bf2f_lo(h2.y); a2.w += v2 * bf2f_hi(h2.y);
            a3.x += v3 * bf2f_lo(h3.x); a3.y += v3 * bf2f_hi(h3.x);
            a3.z += v3 * bf2f_lo(h3.y); a3.w += v3 * bf2f_hi(h3.y);
        }
        for (; e < le1; e++) {
            int2 p = cs[e];
            float v = __int_as_float(p.y);
            uint2 hh = *(const uint2*)&Hgb[(size_t)p.x * HID + c0];
            a0.x += v * bf2f_lo(hh.x); a0.y += v * bf2f_hi(hh.x);
            a0.z += v * bf2f_lo(hh.y); a0.w += v * bf2f_hi(hh.y);
        }
        float4 acc = make_float4(a0.x + a1.x + a2.x + a3.x, a0.y + a1.y + a2.y + a3.y,
                                 a0.z + a1.z + a2.z + a3.z, a0.w + a1.w + a2.w + a3.w);
        uint2 o;
        o.x = (unsigned)f2bf(acc.x) | ((unsigned)f2bf(acc.y) << 16);
        o.y = (unsigned)f2bf(acc.z) | ((unsigned)f2bf(acc.w) << 16);
        *(uint2*)&S[(size_t)row * HID + c0] = o;
        sum.x += acc.x; sum.y += acc.y; sum.z += acc.z; sum.w += acc.w;
        sq.x += acc.x * acc.x; sq.y += acc.y * acc.y;
        sq.z += acc.z * acc.z; sq.w += acc.w * acc.w;
    }

    *(float4*)&rs[g][c0] = sum;
    *(float4*)&rq[g][c0] = sq;
    __syncthreads();
    if (t < HID) {
        float a = 0.f, bb = 0.f;
        for (int w = 0; w < 16; w++) { a += rs[w][t]; bb += rq[w][t]; }
        int stripe = b & 7;
        atomicAdd(&stats[stripe * 128 + t], a);
        atomicAdd(&stats[stripe * 128 + HID + t], bb);
    }
}

// ---------------------------------------------------------------------------
// MFMA dual-GEMM body. [Hn | Hg] = act(X) @ [Wn | Wg] (+ per-col biases);
// Hg always bf16 out; Hn bf16 (HNBF) or fp32. X fp32 or bf16 (XBF).
// AFF: BN scale/shift recomputed in-block from striped sums.
// Epilogue: bf16 outputs staged through LDS (reusing Xs) -> coalesced uint4.
// ---------------------------------------------------------------------------

template <int K, int HOUT, bool AFF, bool XBF, bool HNBF>
__device__ void gemm_body(const void* __restrict__ Xv, const unsigned short* __restrict__ Wp,
                          const float* __restrict__ bnA, const float* __restrict__ bnB,
                          const float* __restrict__ bgA,
                          const float* __restrict__ sums, const float* __restrict__ gamma,
                          const float* __restrict__ beta,
                          float* __restrict__ Hnf, unsigned short* __restrict__ Hnb,
                          unsigned short* __restrict__ Hgb, int n, int blk)
{
    constexpr int NT = 2 * HOUT / 16, NKB = K / 32;
    constexpr int RS = K + 8;                       // staging row stride (shorts)
    constexpr int OC = HNBF ? 2 * HOUT : HOUT;      // cols staged through LDS in epilogue
    constexpr int RSE = OC + 8;                     // epilogue row stride (shorts, 16B mult)
    constexpr int XSZ = (RS > RSE) ? RS : RSE;
    __shared__ unsigned short Xs[64 * XSZ];
    __shared__ float sSc[64], sSh[64];

    const int row0 = blk * 64;
    const int t = threadIdx.x;

    if (AFF) {               // in-block BN finalize: 1KB of reads, once per block
        if (t < 64) {
            float sum = 0.f, sq = 0.f;
#pragma unroll
            for (int s = 0; s < 8; s++) { sum += sums[s * 128 + t]; sq += sums[s * 128 + 64 + t]; }
            float m = sum / (float)NNODES;
            float var = sq / (float)NNODES - m * m;
            float sc = gamma[t] * rsqrtf(var + BN_EPS);
            sSc[t] = sc; sSh[t] = beta[t] - m * sc;
        }
        __syncthreads();
    }

    // Stage 64 x K -> bf16 LDS. Loads batched first (row-clamped, unconditional),
    // then convert (+affine+relu) and ds_write.
    constexpr int SIT = K / 32;      // staging iterations per thread (256 thr)
    if constexpr (XBF) {
        uint4 u[SIT];
#pragma unroll
        for (int it = 0; it < SIT; it++) {
            int li = it * 256 + t;
            int rr = row0 + li / (K / 8);
            int k8 = (li % (K / 8)) * 8;
            int rc = rr < n ? rr : n - 1;
            u[it] = *(const uint4*)((const unsigned short*)Xv + (size_t)rc * K + k8);
        }
#pragma unroll
        for (int it = 0; it < SIT; it++) {
            int li = it * 256 + t;
            int r  = li / (K / 8);
            int k8 = (li % (K / 8)) * 8;
            float v[8];
            v[0] = bf2f_lo(u[it].x); v[1] = bf2f_hi(u[it].x);
            v[2] = bf2f_lo(u[it].y); v[3] = bf2f_hi(u[it].y);
            v[4] = bf2f_lo(u[it].z); v[5] = bf2f_hi(u[it].z);
            v[6] = bf2f_lo(u[it].w); v[7] = bf2f_hi(u[it].w);
            if (AFF) {
#pragma unroll
                for (int i = 0; i < 8; i++) v[i] = fmaxf(v[i] * sSc[k8 + i] + sSh[k8 + i], 0.f);
            }
            uint4 o;
            o.x = (unsigned)f2bf(v[0]) | ((unsigned)f2bf(v[1]) << 16);
            o.y = (unsigned)f2bf(v[2]) | ((unsigned)f2bf(v[3]) << 16);
            o.z = (unsigned)f2bf(v[4]) | ((unsigned)f2bf(v[5]) << 16);
            o.w = (unsigned)f2bf(v[6]) | ((unsigned)f2bf(v[7]) << 16);
            *(uint4*)&Xs[r * RS + k8] = o;
        }
    } else {
        const float* Xf = (const float*)Xv;
        float4 a[SIT], b[SIT];
#pragma unroll
        for (int it = 0; it < SIT; it++) {
            int li = it * 256 + t;
            int rr = row0 + li / (K / 8);
            int k8 = (li % (K / 8)) * 8;
            int rc = rr < n ? rr : n - 1;
            a[it] = *(const float4*)&Xf[(size_t)rc * K + k8];
            b[it] = *(const float4*)&Xf[(size_t)rc * K + k8 + 4];
        }
#pragma unroll
        for (int it = 0; it < SIT; it++) {
            int li = it * 256 + t;
            int r  = li / (K / 8);
            int k8 = (li % (K / 8)) * 8;
            float v[8] = { a[it].x, a[it].y, a[it].z, a[it].w,
                           b[it].x, b[it].y, b[it].z, b[it].w };
            if (AFF) {
#pragma unroll
                for (int i = 0; i < 8; i++) v[i] = fmaxf(v[i] * sSc[k8 + i] + sSh[k8 + i], 0.f);
            }
            uint4 o;
            o.x = (unsigned)f2bf(v[0]) | ((unsigned)f2bf(v[1]) << 16);
            o.y = (unsigned)f2bf(v[2]) | ((unsigned)f2bf(v[3]) << 16);
            o.z = (unsigned)f2bf(v[4]) | ((unsigned)f2bf(v[5]) << 16);
            o.w = (unsigned)f2bf(v[6]) | ((unsigned)f2bf(v[7]) << 16);
            *(uint4*)&Xs[r * RS + k8] = o;
        }
    }
    __syncthreads();

    const int wave = t >> 6, lane = t & 63;
    const int q = lane >> 4, mrow = lane & 15;

    f32x4 acc[NT];
#pragma unroll
    for (int i = 0; i < NT; i++) acc[i] = (f32x4){0.f, 0.f, 0.f, 0.f};

    const short8* wp8 = (const short8*)Wp;
#pragma unroll
    for (int kb = 0; kb < NKB; kb++) {
        short8 va = *(const short8*)&Xs[(wave * 16 + mrow) * RS + kb * 32 + q * 8];
#pragma unroll
        for (int tt = 0; tt < NT; tt++) {
            short8 vb = wp8[(kb * NT + tt) * 64 + lane];   // coalesced dwordx4
            acc[tt] = __builtin_amdgcn_mfma_f32_16x16x32_bf16(va, vb, acc[tt], 0, 0, 0);
        }
    }

    // Epilogue. C/D: col = lane&15 (tile tt), row = q*4 + reg.
    // bf16 outputs -> LDS (reuse Xs) -> coalesced uint4 stores.
    __syncthreads();          // all waves done reading staging Xs
#pragma unroll
    for (int tt = 0; tt < NT; tt++) {
        int nglob = tt * 16 + mrow;
        bool nside = (nglob < HOUT);
        int c = nside ? nglob : (nglob - HOUT);
        float bias = 0.f;
        if (nside) {
            if (bnA) bias += bnA[c];
            if (bnB) bias += bnB[c];
        } else if (bgA) {
            bias += bgA[c];
        }
        if (HNBF || !nside) {
            int cc = HNBF ? nglob : c;
#pragma unroll
            for (int r = 0; r < 4; r++)
                Xs[(wave * 16 + q * 4 + r) * RSE + cc] = f2bf(acc[tt][r] + bias);
        } else {
            // fp32 Hn half (last layer only): direct stores
#pragma unroll
            for (int r = 0; r < 4; r++) {
                int rr = row0 + wave * 16 + q * 4 + r;
                if (rr < n) Hnf[(size_t)rr * HOUT + c] = acc[tt][r] + bias;
            }
        }
    }
    __syncthreads();
    constexpr int J = OC / 8;                 // uint4 per row
#pragma unroll
    for (int u2 = 0; u2 < (64 * J) / 256; u2++) {
        int li = u2 * 256 + t;
        int r = li / J, j = li % J;
        int rr = row0 + r;
        if (rr < n) {
            uint4 v = *(const uint4*)&Xs[r * RSE + j * 8];
            int c8 = j * 8;
            if (HNBF && c8 < HOUT)
                *(uint4*)&Hnb[(size_t)rr * HOUT + c8] = v;
            else
                *(uint4*)&Hgb[(size_t)rr * HOUT + (HNBF ? c8 - HOUT : c8)] = v;
        }
    }
}

// K_C: blocks [0,NCHK*PF): bucket-partition. Each chunk is handled by PF
//      blocks; sibling blocks are mapped chunk = i % NCHK, pf = i / NCHK so
//      all PF siblings of a chunk share i%8 (same XCD under round-robin
//      dispatch) -> the chunk's rows/cols/vals are fetched once per XCD L2.
//      rows+cols+vals streamed as coalesced int4/float4.
//      blocks [NCHK*PF,..): layer-0 dual GEMM (co-scheduled, independent).
__global__ __launch_bounds__(256) void part_gemm0_k(
    const int* __restrict__ rows, const int* __restrict__ cols,
    const float* __restrict__ vals, const int* __restrict__ BcntT,
    const int* __restrict__ bBase, uint2* __restrict__ ebuf,
    const float* __restrict__ X, const unsigned short* __restrict__ Wp0,
    const float* __restrict__ bn0, const float* __restrict__ ab0, const float* __restrict__ bg0,
    unsigned short* __restrict__ Hn0b, unsigned short* __restrict__ Hgb, int n)
{
    if ((int)blockIdx.x < NCHK * PF) {
        __shared__ int cur[NBF];
        int t = threadIdx.x;
        int blk = blockIdx.x % NCHK;          // sibling co-location: i%8 == blk%8
        int pf  = blockIdx.x / NCHK;
        int b0 = pf * NBF, b1 = (pf == PF - 1) ? NB : (b0 + NBF);
        for (int b = b0 + t; b < b1; b += 256)
            cur[b - b0] = bBase[b] + BcntT[blk * NB + b];
        __syncthreads();
        constexpr int EC4 = EC / 4;           // 3125 int4 reads per chunk stream
        const int*   rbase = rows + blk * EC;
        const int*   cbase = cols + blk * EC;
        const float* vbase = vals + blk * EC;
        for (int i4 = t; i4 < EC4; i4 += 256) {
            int4   r4 = *(const int4*)&rbase[i4 * 4];
            int4   c4 = *(const int4*)&cbase[i4 * 4];
            float4 v4 = *(const float4*)&vbase[i4 * 4];
#pragma unroll
            for (int j = 0; j < 4; j++) {
                int r = (&r4.x)[j];
                int b = r >> 6;
                if (b >= b0 && b < b1) {
                    int p = atomicAdd(&cur[b - b0], 1);    // LDS atomic
                    ebuf[p] = make_uint2(((unsigned)(r & 63) << 20) | (unsigned)(&c4.x)[j],
                                         (unsigned)__float_as_int((&v4.x)[j]));
                }
            }
        }
    } else {
        gemm_body<DIN, HID, false, false, true>(X, Wp0, bn0, ab0, bg0,
            nullptr, nullptr, nullptr, nullptr, Hn0b, Hgb, n, blockIdx.x - NCHK * PF);
    }
}

template <int K, int HOUT, bool AFF, bool XBF, bool HNBF>
__global__ __launch_bounds__(256) void gemm_k(
    const void* __restrict__ X, const unsigned short* __restrict__ Wp,
    const float* __restrict__ bnA, const float* __restrict__ bnB, const float* __restrict__ bgA,
    const float* __restrict__ sums, const float* __restrict__ gamma, const float* __restrict__ beta,
    float* __restrict__ Hnf, unsigned short* __restrict__ Hnb, unsigned short* __restrict__ Hgb, int n)
{
    gemm_body<K, HOUT, AFF, XBF, HNBF>(X, Wp, bnA, bnB, bgA, sums, gamma, beta,
                                       Hnf, Hnb, Hgb, n, blockIdx.x);
}

// ---------------------------------------------------------------------------
// SpMM v2 (block-local CSR staging): each block owns 64 CONSECUTIVE rows;
// stages rowptr[65] + the block's whole edge segment (~512 edges) into LDS
// with coalesced loads; groups then read edges from LDS (broadcast,
// conflict-free) and issue only the Hgb gathers. Overflow (>1024 edges)
// falls back to direct global reads per row.
// ---------------------------------------------------------------------------

template <int HH, bool STATS, bool SBF, bool MARKED>
__global__ __launch_bounds__(256) void spmm_k(
    const int* __restrict__ rowptr, const int2* __restrict__ cs,
    const unsigned short* __restrict__ Hgb, void* __restrict__ Sv,
    float* __restrict__ stats, const int* __restrict__ mark, int n)
{
    constexpr int L   = HH / 4;     // lanes per group (16 or 8)
    constexpr int GP  = 256 / L;    // groups per block (16 or 32)
    constexpr int RPB = 64;         // rows per block (consecutive)
    constexpr int RPG = RPB / GP;   // rows per group (4 or 2)
    constexpr int ECAP = 1024;      // staged-edge capacity (8KB)
    __shared__ int2 es[ECAP];
    __shared__ int  rp[RPB + 1];

    const int t = threadIdx.x;
    const int R0 = blockIdx.x * RPB;
    if (t <= RPB) rp[t] = rowptr[min(R0 + t, n)];
    __syncthreads();
    const int e0b  = rp[0];
    const int scnt = min(rp[RPB] - e0b, ECAP);
    for (int i = t; i < scnt; i += 256) es[i] = cs[e0b + i];   // coalesced 8B
    __syncthreads();

    const int lane = t % L;
    const int g    = t / L;
    const int c0   = lane * 4;

    float4 sum = make_float4(0.f, 0.f, 0.f, 0.f);
    float4 sq  = make_float4(0.f, 0.f, 0.f, 0.f);

#define SPMM_ROW(FETCH)                                                            \
    {                                                                              \
        int e = le0;                                                               \
        for (; e + 3 < le1; e += 4) {                                              \
            int2 p0 = FETCH(e), p1 = FETCH(e + 1), p2 = FETCH(e + 2), p3 = FETCH(e + 3); \
            float v0 = __int_as_float(p0.y), v1 = __int_as_float(p1.y);            \
            float v2 = __int_as_float(p2.y), v3 = __int_as_float(p3.y);            \
            uint2 h0 = *(const uint2*)&Hgb[(size_t)p0.x * HH + c0];                \
            uint2 h1 = *(const uint2*)&Hgb[(size_t)p1.x * HH + c0];                \
            uint2 h2 = *(const uint2*)&Hgb[(size_t)p2.x * HH + c0];                \
            uint2 h3 = *(const uint2*)&Hgb[(size_t)p3.x * HH + c0];                \
            a0.x += v0 * bf2f_lo(h0.x); a0.y += v0 * bf2f_hi(h0.x);                \
            a0.z += v0 * bf2f_lo(h0.y); a0.w += v0 * bf2f_hi(h0.y);                \
            a1.x += v1 * bf2f_lo(h1.x); a1.y += v1 * bf2f_hi(h1.x);                \
            a1.z += v1 * bf2f_lo(h1.y); a1.w += v1 * bf2f_hi(h1.y);                \
            a2.x += v2 * bf2f_lo(h2.x); a2.y += v2 * bf2f_hi(h2.x);                \
            a2.z += v2 * bf2f_lo(h2.y); a2.w += v2 * bf2f_hi(h2.y);                \
            a3.x += v3 * bf2f_lo(h3.x); a3.y += v3 * bf2f_hi(h3.x);                \
            a3.z += v3 * bf2f_lo(h3.y); a3.w += v3 * bf2f_hi(h3.y);                \
        }                                                                          \
        for (; e < le1; e++) {                                                     \
            int2 p = FETCH(e);                                                     \
            float v = __int_as_float(p.y);                                         \
            uint2 h = *(const uint2*)&Hgb[(size_t)p.x * HH + c0];                  \
            a0.x += v * bf2f_lo(h.x); a0.y += v * bf2f_hi(h.x);                    \
            a0.z += v * bf2f_lo(h.y); a0.w += v * bf2f_hi(h.y);                    \
        }                                                                          \
    }
#define F_LDS(i) es[(i)]
#define F_GLB(i) cs[e0b + (i)]

#pragma unroll
    for (int rr = 0; rr < RPG; rr++) {
        int row = R0 + g * RPG + rr;
        if (row >= n) break;
        if (MARKED && !mark[row]) continue;
        int le0 = rp[g * RPG + rr] - e0b;
        int le1 = rp[g * RPG + rr + 1] - e0b;
        float4 a0, a1, a2, a3;
        if (SBF) {
            uint2 h = *(const uint2*)((const unsigned short*)Sv + (size_t)row * HH + c0);
            a0 = make_float4(bf2f_lo(h.x), bf2f_hi(h.x), bf2f_lo(h.y), bf2f_hi(h.y));
        } else {
            a0 = *(const float4*)((const float*)Sv + (size_t)row * HH + c0);
        }
        a1 = a2 = a3 = make_float4(0.f, 0.f, 0.f, 0.f);
        if (le1 <= scnt) SPMM_ROW(F_LDS) else SPMM_ROW(F_GLB);
        float4 acc = make_float4(a0.x + a1.x + a2.x + a3.x, a0.y + a1.y + a2.y + a3.y,
                                 a0.z + a1.z + a2.z + a3.z, a0.w + a1.w + a2.w + a3.w);
        if (SBF) {
            uint2 o;
            o.x = (unsigned)f2bf(acc.x) | ((unsigned)f2bf(acc.y) << 16);
            o.y = (unsigned)f2bf(acc.z) | ((unsigned)f2bf(acc.w) << 16);
            *(uint2*)((unsigned short*)Sv + (size_t)row * HH + c0) = o;
        } else {
            *(float4*)((float*)Sv + (size_t)row * HH + c0) = acc;
        }
        if (STATS) {
            sum.x += acc.x; sum.y += acc.y; sum.z += acc.z; sum.w += acc.w;
            sq.x += acc.x * acc.x; sq.y += acc.y * acc.y;
            sq.z += acc.z * acc.z; sq.w += acc.w * acc.w;
        }
    }
#undef SPMM_ROW
#undef F_LDS
#undef F_GLB

    if constexpr (STATS) {
        __shared__ float rs[GP][HH];
        __shared__ float rq[GP][HH];
        *(float4*)&rs[g][c0] = sum;
        *(float4*)&rq[g][c0] = sq;
        __syncthreads();
        if (threadIdx.x < HH) {
            float a = 0.f, b = 0.f;
            for (int w = 0; w < GP; w++) { a += rs[w][threadIdx.x]; b += rq[w][threadIdx.x]; }
            int stripe = blockIdx.x & 7;
            atomicAdd(&stats[stripe * 128 + threadIdx.x], a);
            atomicAdd(&stats[stripe * 128 + HH + threadIdx.x], b);
        }
    }
}

__global__ void gather_k(const float* __restrict__ S, const int* __restrict__ idx,
                         float* __restrict__ out, int total4) {
    int j = blockIdx.x * 256 + threadIdx.x;
    if (j < total4) {
        int r = j / (EMB / 4), c4 = (j % (EMB / 4)) * 4;
        *(float4*)&out[(size_t)j * 4] = *(const float4*)&S[(size_t)idx[r] * EMB + c4];
    }
}

// ---------------------------------------------------------------------------

extern "C" void kernel_launch(void* const* d_in, const int* in_sizes, int n_in,
                              void* d_out, int out_size, void* d_ws, size_t ws_size,
                              hipStream_t stream) {
    const float* features = (const float*)d_in[0];
    const int*   rows     = (const int*)d_in[1];
    const int*   cols     = (const int*)d_in[2];
    const float* vals     = (const float*)d_in[3];
    const int*   idx      = (const int*)d_in[4];
    const float* Wn0 = (const float*)d_in[5];
    const float* bn0 = (const float*)d_in[6];
    const float* Wg0 = (const float*)d_in[7];
    const float* bg0 = (const float*)d_in[8];
    const float* ab0 = (const float*)d_in[9];
    const float* g0  = (const float*)d_in[10];
    const float* b0  = (const float*)d_in[11];
    const float* Wn1 = (const float*)d_in[12];
    const float* Wg1 = (const float*)d_in[13];
    const float* ab1 = (const float*)d_in[14];
    const float* g1  = (const float*)d_in[15];
    const float* b1  = (const float*)d_in[16];
    const float* WnL = (const float*)d_in[17];
    const float* WgL = (const float*)d_in[18];
    const float* abL = (const float*)d_in[19];
    float* out = (float*)d_out;

    // Workspace layout (~65 MB), 16B-aligned sub-buffers.
    float*          HnLf = (float*)d_ws;                        // N x EMB fp32 (HnL/SL)
    unsigned short* nA   = (unsigned short*)(HnLf + (size_t)NNODES * EMB); // Hn0/S0 bf16
    unsigned short* nB   = nA + (size_t)NNODES * HID;           // Hn1/S1 bf16
    unsigned short* Hgb  = nB + (size_t)NNODES * HID;           // Hg (all layers) bf16
    uint2* ebuf  = (uint2*)(Hgb + (size_t)NNODES * HID);        // E x 8B (packed)
    int2*  cs    = (int2*)(ebuf + NEDGES);                      // E (row-sorted payload)
    int*   rowptr = (int*)(cs + NEDGES);                        // N+4
    int*   Bcnt4 = rowptr + (NNODES + 4);                       // NCHK x NB
    int*   BcntT = Bcnt4 + NCHK * NB;                           // NCHK x NB
    int*   bBase = BcntT + NCHK * NB;                           // NB+1 (pad 1568)
    unsigned short* Wp0 = (unsigned short*)(bBase + 1568);      // 16384
    unsigned short* Wp1 = Wp0 + 16384;                          // 8192
    unsigned short* WpL = Wp1 + 8192;                           // 4096
    // ---- single zeroed region: stats | mark | bTot ----
    float* stats = (float*)(WpL + 4096);                        // 2304
    int*   mark  = (int*)(stats + 2304);                        // N
    int*   bTot  = mark + NNODES;                               // 1568
    float* sums0 = stats;
    float* sums1 = stats + 1024;
    size_t zbytes = 2304 * 4 + (size_t)NNODES * 4 + 1568 * 4;

    hipMemsetAsync(stats, 0, zbytes, stream);

    const int GBm = (NNODES + 63) / 64;     // 1563
    const int MB  = (NIDX + 255) / 256;     // 196

    // K1: per-chunk bucket histogram (+bTot atomics) + mark + W pre-pack.
    histpack_k<<<NCHK + MB + 112, 256, 0, stream>>>(
        rows, Bcnt4, bTot, idx, mark, Wn0, Wg0, Wn1, Wg1, WnL, WgL, Wp0, Wp1, WpL, MB);
    // ONE dispatch: chunk-prefix (blocks 0-6) + bucket-base scan (block 7).
    scan_k<<<8, 256, 0, stream>>>(Bcnt4, BcntT, bTot, bBase);
    part_gemm0_k<<<NCHK * PF + GBm, 256, 0, stream>>>(rows, cols, vals, BcntT, bBase, ebuf,
                                                      features, Wp0, bn0, ab0, bg0,
                                                      nA, Hgb, NNODES);
    // FUSED: bucket sort -> rowptr/cs AND layer-0 aggregate S0 = Hn0 + A@Hg0
    bfinal_spmm0_k<<<NB, 256, 0, stream>>>(ebuf, bBase, rowptr, cs, Hgb, nA, sums0, NNODES);

    // Layer 1: BN finalize folded into gemm; S1 = Hn1 + ab1 + A@Hg1
    gemm_k<HID, HID, true, true, true><<<GBm, 256, 0, stream>>>(
        nA, Wp1, ab1, nullptr, nullptr, sums0, g0, b0, nullptr, nB, Hgb, NNODES);
    spmm_k<HID, true, true, false><<<GBm, 256, 0, stream>>>(rowptr, cs, Hgb, nB, sums1, nullptr, NNODES);

    // Last layer: HnL fp32; aggregate only rows referenced by idx.
    gemm_k<HID, EMB, true, true, false><<<GBm, 256, 0, stream>>>(
        nB, WpL, abL, nullptr, nullptr, sums1, g1, b1, HnLf, nullptr, Hgb, NNODES);
    spmm_k<EMB, false, false, true><<<GBm, 256, 0, stream>>>(rowptr, cs, Hgb, HnLf, nullptr, mark, NNODES);

    gather_k<<<(NIDX * EMB / 4 + 255) / 256, 256, 0, stream>>>(HnLf, idx, out, NIDX * EMB / 4);
}

// Round 10
// 251.772 us; speedup vs baseline: 1.2924x; 1.0246x over previous
//
#include <hip/hip_runtime.h>

// Problem constants (fixed by the reference).
#define NNODES 100000
#define NEDGES 800000
#define DIN    128
#define HID    64
#define EMB    32
#define NIDX   50000
#define BN_EPS 1e-5f

#define NCHK 64                   // partition chunks (64 -> ~8-edge runs per bucket, 64B)
#define EC   (NEDGES / NCHK)      // 12500 edges per chunk
#define NB   ((NNODES + 63) / 64) // 1563 row-buckets of 64 rows
#define PF   16                   // bucket fractions per chunk (scatter parallelism)
#define NBF  ((NB + PF - 1) / PF) // 98 buckets per fraction

typedef __attribute__((ext_vector_type(8))) short short8;   // 8 bf16 = 4 VGPR
typedef __attribute__((ext_vector_type(4))) float f32x4;    // MFMA C/D

__device__ inline unsigned short f2bf(float f) {            // RNE, matches HW
    unsigned u = __float_as_uint(f);
    unsigned r = u + 0x7FFFu + ((u >> 16) & 1u);
    return (unsigned short)(r >> 16);
}
__device__ inline float bf2f_lo(unsigned u) { return __uint_as_float(u << 16); }
__device__ inline float bf2f_hi(unsigned u) { return __uint_as_float(u & 0xffff0000u); }

// ---------------------------------------------------------------------------
// W pre-pack: fp32 [Wn|Wg] -> bf16 B-fragment-major (GEMM B-loads coalesced).
// ---------------------------------------------------------------------------

__device__ inline void pack_seg(const float* __restrict__ Wn, const float* __restrict__ Wg,
                                unsigned short* __restrict__ Wp, int HOUT, int l2nt, int f) {
    int j = f & 7, lane = (f >> 3) & 63, g = f >> 9;
    int tt = g & ((1 << l2nt) - 1), kb = g >> l2nt;
    int k = kb * 32 + ((lane >> 4) * 8) + j;
    int nn = tt * 16 + (lane & 15);
    float v = (nn < HOUT) ? Wn[k * HOUT + nn] : Wg[k * HOUT + (nn - HOUT)];
    Wp[f] = f2bf(v);
}

// ---------------------------------------------------------------------------
// K1: blocks [0,NCHK): per-chunk bucket histogram -> Bcnt4[chunk][b]
//     + bucket totals bTot[b] via global atomics (breaks prefix/scan dep).
//     blocks [NCHK,NCHK+MB): mark[idx[j]] = 1
//     blocks [NCHK+MB,..): W pre-pack (all 3 layers)  -- all independent.
// ---------------------------------------------------------------------------

__global__ __launch_bounds__(256) void histpack_k(
    const int* __restrict__ rows, int* __restrict__ Bcnt4, int* __restrict__ bTot,
    const int* __restrict__ idx, int* __restrict__ mark,
    const float* Wn0, const float* Wg0, const float* Wn1,
    const float* Wg1, const float* WnL, const float* WgL,
    unsigned short* Wp0, unsigned short* Wp1, unsigned short* WpL, int MB)
{
    int blk = blockIdx.x;
    int t = threadIdx.x;
    if (blk >= NCHK + MB) {
        int f = (blk - NCHK - MB) * 256 + t;
        if (f < 16384)      pack_seg(Wn0, Wg0, Wp0, 64, 3, f);           // 128x128
        else if (f < 24576) pack_seg(Wn1, Wg1, Wp1, 64, 3, f - 16384);   // 64x128
        else if (f < 28672) pack_seg(WnL, WgL, WpL, 32, 2, f - 24576);   // 64x64
        return;
    }
    if (blk >= NCHK) {
        int j = (blk - NCHK) * 256 + t;
        if (j < NIDX) mark[idx[j]] = 1;
        return;
    }
    __shared__ int hist[NB];
    for (int b = t; b < NB; b += 256) hist[b] = 0;
    __syncthreads();
    const int* rbase = rows + blk * EC;
    for (int i4 = t; i4 < EC / 4; i4 += 256) {           // 3125 int4 reads
        int4 r4 = *(const int4*)&rbase[i4 * 4];
        atomicAdd(&hist[r4.x >> 6], 1);
        atomicAdd(&hist[r4.y >> 6], 1);
        atomicAdd(&hist[r4.z >> 6], 1);
        atomicAdd(&hist[r4.w >> 6], 1);
    }
    __syncthreads();
    for (int b = t; b < NB; b += 256) {
        int h = hist[b];
        Bcnt4[blk * NB + b] = h;
        if (h) atomicAdd(&bTot[b], h);                   // device-scope
    }
}

// scan_k: ONE dispatch, two independent jobs (both depend only on histpack):
//   blocks 0..6: per-bucket prefix over chunks -> BcntT[chunk][b]
//   block 7:     exclusive scan of bTot -> bBase (bucket bases)
__global__ __launch_bounds__(256) void scan_k(
    const int* __restrict__ Bcnt4, int* __restrict__ BcntT,
    const int* __restrict__ bTot, int* __restrict__ bBase)
{
    int t = threadIdx.x;
    if (blockIdx.x < 7) {
        int b = blockIdx.x * 256 + t;
        if (b >= NB) return;
        int run = 0;
        for (int c = 0; c < NCHK; c++) {
            BcntT[c * NB + b] = run;     // coalesced read & write
            run += Bcnt4[c * NB + b];
        }
        return;
    }
    __shared__ int s[256];
    int v[7], loc = 0;
#pragma unroll
    for (int i = 0; i < 7; i++) {
        int ix = t * 7 + i;
        v[i] = loc;
        loc += (ix < NB) ? bTot[ix] : 0;
    }
    s[t] = loc;
    __syncthreads();
    for (int off = 1; off < 256; off <<= 1) {
        int a = (t >= off) ? s[t - off] : 0;
        __syncthreads();
        s[t] += a;
        __syncthreads();
    }
    int base = s[t] - loc;
#pragma unroll
    for (int i = 0; i < 7; i++) {
        int ix = t * 7 + i;
        if (ix < NB) bBase[ix] = base + v[i];
    }
    if (t == 255) bBase[NB] = NEDGES;
}

// ---------------------------------------------------------------------------
// bfinal+spmm0 FUSED v2: one block per bucket (64 rows, ~512 edges).
// Single ebuf pass: each thread holds its <=4 edges in named registers while
// building the LDS histogram; after the local scan, scatters them into LDS
// es2[] (bucket-local sorted order); es2 is dumped to cs with fully coalesced
// stores; the spmm0 phase consumes edges straight from LDS (cs never re-read).
// Overflow (>1024 edges/bucket, +22 sigma) falls back to global cs.
// ---------------------------------------------------------------------------

__global__ __launch_bounds__(256) void bfinal_spmm0_k(
    const uint2* __restrict__ ebuf, const int* __restrict__ bBase,
    int* __restrict__ rowptr, int2* __restrict__ cs,
    const unsigned short* __restrict__ Hgb, unsigned short* __restrict__ S,
    float* __restrict__ stats, int n)
{
    constexpr int ECAP = 1024;
    __shared__ int hist[64], sc[64], cur[64];
    __shared__ int2 es2[ECAP];               // bucket-local sorted edges
    __shared__ float rs[16][HID], rq[16][HID];
    int b = blockIdx.x, t = threadIdx.x;
    int e0 = bBase[b], e1 = bBase[b + 1];
    int cnt = e1 - e0;
    int r0 = b << 6;
    if (t < 64) hist[t] = 0;
    __syncthreads();

    // pass 1: load edges once (named registers), build histogram
    uint2 ev0, ev1, ev2, ev3;
    bool h0 = t < cnt, h1 = t + 256 < cnt, h2 = t + 512 < cnt, h3 = t + 768 < cnt;
    if (h0) { ev0 = ebuf[e0 + t];       atomicAdd(&hist[(ev0.x >> 20) & 63], 1); }
    if (h1) { ev1 = ebuf[e0 + t + 256]; atomicAdd(&hist[(ev1.x >> 20) & 63], 1); }
    if (h2) { ev2 = ebuf[e0 + t + 512]; atomicAdd(&hist[(ev2.x >> 20) & 63], 1); }
    if (h3) { ev3 = ebuf[e0 + t + 768]; atomicAdd(&hist[(ev3.x >> 20) & 63], 1); }
    for (int i = t + ECAP; i < cnt; i += 256) {          // overflow tail (rare)
        uint2 v = ebuf[e0 + i];
        atomicAdd(&hist[(v.x >> 20) & 63], 1);
    }
    __syncthreads();
    if (t == 0) {
        int run = 0;                                     // LOCAL (0-based) scan
        for (int j = 0; j < 64; j++) { sc[j] = run; run += hist[j]; }
    }
    __syncthreads();
    if (t < 64) {
        cur[t] = sc[t];
        int r = r0 + t;
        if (r < NNODES) rowptr[r] = e0 + sc[t];
    }
    if (b == NB - 1 && t == 0) rowptr[NNODES] = NEDGES;
    __syncthreads();

    // pass 2: scatter registers -> es2 (LDS), overflow -> cs directly
#define SCAT(V)                                                          \
    {                                                                    \
        int p = atomicAdd(&cur[((V).x >> 20) & 63], 1);                  \
        int2 pay = make_int2((int)((V).x & 0xFFFFF), (int)(V).y);        \
        if (p < ECAP) es2[p] = pay; else cs[e0 + p] = pay;               \
    }
    if (h0) SCAT(ev0)
    if (h1) SCAT(ev1)
    if (h2) SCAT(ev2)
    if (h3) SCAT(ev3)
    for (int i = t + ECAP; i < cnt; i += 256) {
        uint2 v = ebuf[e0 + i];
        SCAT(v)
    }
#undef SCAT
    __syncthreads();                 // es2 complete; overflow cs writes drained

    // pass 3: coalesced dump es2 -> cs (runs concurrent with spmm0 phase loads)
    int scnt = min(cnt, ECAP);
    for (int i = t; i < scnt; i += 256) cs[e0 + i] = es2[i];

    // ---- spmm0 phase: 16 groups x 16 lanes, 4 consecutive rows per group ----
    // Edges sourced from LDS (i < ECAP) or global cs (overflow, pre-barrier).
    const int lane = t & 15, g = t >> 4;
    const int c0 = lane * 4;
    float4 sum = make_float4(0.f, 0.f, 0.f, 0.f);
    float4 sq  = make_float4(0.f, 0.f, 0.f, 0.f);
#define FE(i) ((i) < ECAP ? es2[(i)] : cs[e0 + (i)])
#pragma unroll
    for (int rr = 0; rr < 4; rr++) {
        int lr = g * 4 + rr;
        int row = r0 + lr;
        if (row >= n) break;
        int le0 = sc[lr], le1 = sc[lr] + hist[lr];       // local indices
        uint2 h = *(const uint2*)&S[(size_t)row * HID + c0];
        float4 a0 = make_float4(bf2f_lo(h.x), bf2f_hi(h.x), bf2f_lo(h.y), bf2f_hi(h.y));
        float4 a1 = make_float4(0.f, 0.f, 0.f, 0.f), a2 = a1, a3 = a1;
        int e = le0;
        for (; e + 3 < le1; e += 4) {
            int2 p0 = FE(e), p1 = FE(e + 1), p2 = FE(e + 2), p3 = FE(e + 3);
            float v0 = __int_as_float(p0.y), v1 = __int_as_float(p1.y);
            float v2 = __int_as_float(p2.y), v3 = __int_as_float(p3.y);
            uint2 h0v = *(const uint2*)&Hgb[(size_t)p0.x * HID + c0];
            uint2 h1v = *(const uint2*)&Hgb[(size_t)p1.x * HID + c0];
            uint2 h2v = *(const uint2*)&Hgb[(size_t)p2.x * HID + c0];
            uint2 h3v = *(const uint2*)&Hgb[(size_t)p3.x * HID + c0];
            a0.x += v0 * bf2f_lo(h0v.x); a0.y += v0 * bf2f_hi(h0v.x);
            a0.z += v0 * bf2f_lo(h0v.y); a0.w += v0 * bf2f_hi(h0v.y);
            a1.x += v1 * bf2f_lo(h1v.x); a1.y += v1 * bf2f_hi(h1v.x);
            a1.z += v1 * bf2f_lo(h1v.y); a1.w += v1 * bf2f_hi(h1v.y);
            a2.x += v2 * bf2f_lo(h2v.x); a2.y += v2 * bf2f_hi(h2v.x);
            a2.z += v2 * bf2f_lo(h2v.y); a2.w += v2 * bf2f_hi(h2v.y);
            a3.x += v3 * bf2f_lo(h3v.x); a3.y += v3 * bf2f_hi(h3v.x);
            a3.z += v3 * bf2f_lo(h3v.y); a3.w += v3 * bf2f_hi(h3v.y);
        }
        for (; e < le1; e++) {
            int2 p = FE(e);
            float v = __int_as_float(p.y);
            uint2 hh = *(const uint2*)&Hgb[(size_t)p.x * HID + c0];
            a0.x += v * bf2f_lo(hh.x); a0.y += v * bf2f_hi(hh.x);
            a0.z += v * bf2f_lo(hh.y); a0.w += v * bf2f_hi(hh.y);
        }
        float4 acc = make_float4(a0.x + a1.x + a2.x + a3.x, a0.y + a1.y + a2.y + a3.y,
                                 a0.z + a1.z + a2.z + a3.z, a0.w + a1.w + a2.w + a3.w);
        uint2 o;
        o.x = (unsigned)f2bf(acc.x) | ((unsigned)f2bf(acc.y) << 16);
        o.y = (unsigned)f2bf(acc.z) | ((unsigned)f2bf(acc.w) << 16);
        *(uint2*)&S[(size_t)row * HID + c0] = o;
        sum.x += acc.x; sum.y += acc.y; sum.z += acc.z; sum.w += acc.w;
        sq.x += acc.x * acc.x; sq.y += acc.y * acc.y;
        sq.z += acc.z * acc.z; sq.w += acc.w * acc.w;
    }
#undef FE

    *(float4*)&rs[g][c0] = sum;
    *(float4*)&rq[g][c0] = sq;
    __syncthreads();
    if (t < HID) {
        float a = 0.f, bb = 0.f;
        for (int w = 0; w < 16; w++) { a += rs[w][t]; bb += rq[w][t]; }
        int stripe = b & 7;
        atomicAdd(&stats[stripe * 128 + t], a);
        atomicAdd(&stats[stripe * 128 + HID + t], bb);
    }
}

// ---------------------------------------------------------------------------
// MFMA dual-GEMM body. [Hn | Hg] = act(X) @ [Wn | Wg] (+ per-col biases);
// Hg always bf16 out; Hn bf16 (HNBF) or fp32. X fp32 or bf16 (XBF).
// AFF: BN scale/shift recomputed in-block from striped sums.
// Epilogue: bf16 outputs staged through LDS (reusing Xs) -> coalesced uint4.
// ---------------------------------------------------------------------------

template <int K, int HOUT, bool AFF, bool XBF, bool HNBF>
__device__ void gemm_body(const void* __restrict__ Xv, const unsigned short* __restrict__ Wp,
                          const float* __restrict__ bnA, const float* __restrict__ bnB,
                          const float* __restrict__ bgA,
                          const float* __restrict__ sums, const float* __restrict__ gamma,
                          const float* __restrict__ beta,
                          float* __restrict__ Hnf, unsigned short* __restrict__ Hnb,
                          unsigned short* __restrict__ Hgb, int n, int blk)
{
    constexpr int NT = 2 * HOUT / 16, NKB = K / 32;
    constexpr int RS = K + 8;                       // staging row stride (shorts)
    constexpr int OC = HNBF ? 2 * HOUT : HOUT;      // cols staged through LDS in epilogue
    constexpr int RSE = OC + 8;                     // epilogue row stride (shorts, 16B mult)
    constexpr int XSZ = (RS > RSE) ? RS : RSE;
    __shared__ unsigned short Xs[64 * XSZ];
    __shared__ float sSc[64], sSh[64];

    const int row0 = blk * 64;
    const int t = threadIdx.x;

    if (AFF) {               // in-block BN finalize: 1KB of reads, once per block
        if (t < 64) {
            float sum = 0.f, sq = 0.f;
#pragma unroll
            for (int s = 0; s < 8; s++) { sum += sums[s * 128 + t]; sq += sums[s * 128 + 64 + t]; }
            float m = sum / (float)NNODES;
            float var = sq / (float)NNODES - m * m;
            float sc = gamma[t] * rsqrtf(var + BN_EPS);
            sSc[t] = sc; sSh[t] = beta[t] - m * sc;
        }
        __syncthreads();
    }

    // Stage 64 x K -> bf16 LDS. Loads batched first (row-clamped, unconditional),
    // then convert (+affine+relu) and ds_write.
    constexpr int SIT = K / 32;      // staging iterations per thread (256 thr)
    if constexpr (XBF) {
        uint4 u[SIT];
#pragma unroll
        for (int it = 0; it < SIT; it++) {
            int li = it * 256 + t;
            int rr = row0 + li / (K / 8);
            int k8 = (li % (K / 8)) * 8;
            int rc = rr < n ? rr : n - 1;
            u[it] = *(const uint4*)((const unsigned short*)Xv + (size_t)rc * K + k8);
        }
#pragma unroll
        for (int it = 0; it < SIT; it++) {
            int li = it * 256 + t;
            int r  = li / (K / 8);
            int k8 = (li % (K / 8)) * 8;
            float v[8];
            v[0] = bf2f_lo(u[it].x); v[1] = bf2f_hi(u[it].x);
            v[2] = bf2f_lo(u[it].y); v[3] = bf2f_hi(u[it].y);
            v[4] = bf2f_lo(u[it].z); v[5] = bf2f_hi(u[it].z);
            v[6] = bf2f_lo(u[it].w); v[7] = bf2f_hi(u[it].w);
            if (AFF) {
#pragma unroll
                for (int i = 0; i < 8; i++) v[i] = fmaxf(v[i] * sSc[k8 + i] + sSh[k8 + i], 0.f);
            }
            uint4 o;
            o.x = (unsigned)f2bf(v[0]) | ((unsigned)f2bf(v[1]) << 16);
            o.y = (unsigned)f2bf(v[2]) | ((unsigned)f2bf(v[3]) << 16);
            o.z = (unsigned)f2bf(v[4]) | ((unsigned)f2bf(v[5]) << 16);
            o.w = (unsigned)f2bf(v[6]) | ((unsigned)f2bf(v[7]) << 16);
            *(uint4*)&Xs[r * RS + k8] = o;
        }
    } else {
        const float* Xf = (const float*)Xv;
        float4 a[SIT], b[SIT];
#pragma unroll
        for (int it = 0; it < SIT; it++) {
            int li = it * 256 + t;
            int rr = row0 + li / (K / 8);
            int k8 = (li % (K / 8)) * 8;
            int rc = rr < n ? rr : n - 1;
            a[it] = *(const float4*)&Xf[(size_t)rc * K + k8];
            b[it] = *(const float4*)&Xf[(size_t)rc * K + k8 + 4];
        }
#pragma unroll
        for (int it = 0; it < SIT; it++) {
            int li = it * 256 + t;
            int r  = li / (K / 8);
            int k8 = (li % (K / 8)) * 8;
            float v[8] = { a[it].x, a[it].y, a[it].z, a[it].w,
                           b[it].x, b[it].y, b[it].z, b[it].w };
            if (AFF) {
#pragma unroll
                for (int i = 0; i < 8; i++) v[i] = fmaxf(v[i] * sSc[k8 + i] + sSh[k8 + i], 0.f);
            }
            uint4 o;
            o.x = (unsigned)f2bf(v[0]) | ((unsigned)f2bf(v[1]) << 16);
            o.y = (unsigned)f2bf(v[2]) | ((unsigned)f2bf(v[3]) << 16);
            o.z = (unsigned)f2bf(v[4]) | ((unsigned)f2bf(v[5]) << 16);
            o.w = (unsigned)f2bf(v[6]) | ((unsigned)f2bf(v[7]) << 16);
            *(uint4*)&Xs[r * RS + k8] = o;
        }
    }
    __syncthreads();

    const int wave = t >> 6, lane = t & 63;
    const int q = lane >> 4, mrow = lane & 15;

    f32x4 acc[NT];
#pragma unroll
    for (int i = 0; i < NT; i++) acc[i] = (f32x4){0.f, 0.f, 0.f, 0.f};

    const short8* wp8 = (const short8*)Wp;
#pragma unroll
    for (int kb = 0; kb < NKB; kb++) {
        short8 va = *(const short8*)&Xs[(wave * 16 + mrow) * RS + kb * 32 + q * 8];
#pragma unroll
        for (int tt = 0; tt < NT; tt++) {
            short8 vb = wp8[(kb * NT + tt) * 64 + lane];   // coalesced dwordx4
            acc[tt] = __builtin_amdgcn_mfma_f32_16x16x32_bf16(va, vb, acc[tt], 0, 0, 0);
        }
    }

    // Epilogue. C/D: col = lane&15 (tile tt), row = q*4 + reg.
    // bf16 outputs -> LDS (reuse Xs) -> coalesced uint4 stores.
    __syncthreads();          // all waves done reading staging Xs
#pragma unroll
    for (int tt = 0; tt < NT; tt++) {
        int nglob = tt * 16 + mrow;
        bool nside = (nglob < HOUT);
        int c = nside ? nglob : (nglob - HOUT);
        float bias = 0.f;
        if (nside) {
            if (bnA) bias += bnA[c];
            if (bnB) bias += bnB[c];
        } else if (bgA) {
            bias += bgA[c];
        }
        if (HNBF || !nside) {
            int cc = HNBF ? nglob : c;
#pragma unroll
            for (int r = 0; r < 4; r++)
                Xs[(wave * 16 + q * 4 + r) * RSE + cc] = f2bf(acc[tt][r] + bias);
        } else {
            // fp32 Hn half (last layer only): direct stores
#pragma unroll
            for (int r = 0; r < 4; r++) {
                int rr = row0 + wave * 16 + q * 4 + r;
                if (rr < n) Hnf[(size_t)rr * HOUT + c] = acc[tt][r] + bias;
            }
        }
    }
    __syncthreads();
    constexpr int J = OC / 8;                 // uint4 per row
#pragma unroll
    for (int u2 = 0; u2 < (64 * J) / 256; u2++) {
        int li = u2 * 256 + t;
        int r = li / J, j = li % J;
        int rr = row0 + r;
        if (rr < n) {
            uint4 v = *(const uint4*)&Xs[r * RSE + j * 8];
            int c8 = j * 8;
            if (HNBF && c8 < HOUT)
                *(uint4*)&Hnb[(size_t)rr * HOUT + c8] = v;
            else
                *(uint4*)&Hgb[(size_t)rr * HOUT + (HNBF ? c8 - HOUT : c8)] = v;
        }
    }
}

// K_C: blocks [0,NCHK*PF): bucket-partition. Each chunk is handled by PF
//      blocks; sibling blocks are mapped chunk = i % NCHK, pf = i / NCHK so
//      all PF siblings of a chunk share i%8 (same XCD under round-robin
//      dispatch) -> the chunk's rows/cols/vals are fetched once per XCD L2.
//      Scan loop software-pipelined: next iteration's int4 loads issue before
//      processing current hits (hides L2/L3 latency across iterations).
//      blocks [NCHK*PF,..): layer-0 dual GEMM (co-scheduled, independent).
__global__ __launch_bounds__(256) void part_gemm0_k(
    const int* __restrict__ rows, const int* __restrict__ cols,
    const float* __restrict__ vals, const int* __restrict__ BcntT,
    const int* __restrict__ bBase, uint2* __restrict__ ebuf,
    const float* __restrict__ X, const unsigned short* __restrict__ Wp0,
    const float* __restrict__ bn0, const float* __restrict__ ab0, const float* __restrict__ bg0,
    unsigned short* __restrict__ Hn0b, unsigned short* __restrict__ Hgb, int n)
{
    if ((int)blockIdx.x < NCHK * PF) {
        __shared__ int cur[NBF];
        int t = threadIdx.x;
        int blk = blockIdx.x % NCHK;          // sibling co-location: i%8 == blk%8
        int pf  = blockIdx.x / NCHK;
        int b0 = pf * NBF, b1 = (pf == PF - 1) ? NB : (b0 + NBF);
        for (int b = b0 + t; b < b1; b += 256)
            cur[b - b0] = bBase[b] + BcntT[blk * NB + b];
        __syncthreads();
        constexpr int EC4 = EC / 4;           // 3125 int4 reads per chunk stream
        const int*   rbase = rows + blk * EC;
        const int*   cbase = cols + blk * EC;
        const float* vbase = vals + blk * EC;
        int i4 = t;
        int4 r4, c4; float4 v4;
        if (i4 < EC4) {
            r4 = *(const int4*)&rbase[i4 * 4];
            c4 = *(const int4*)&cbase[i4 * 4];
            v4 = *(const float4*)&vbase[i4 * 4];
        }
        while (i4 < EC4) {
            int4 rr = r4; int4 cc = c4; float4 vv = v4;
            int ni = i4 + 256;
            if (ni < EC4) {                    // prefetch next iteration
                r4 = *(const int4*)&rbase[ni * 4];
                c4 = *(const int4*)&cbase[ni * 4];
                v4 = *(const float4*)&vbase[ni * 4];
            }
#pragma unroll
            for (int j = 0; j < 4; j++) {
                int r = (&rr.x)[j];
                int b = r >> 6;
                if (b >= b0 && b < b1) {
                    int p = atomicAdd(&cur[b - b0], 1);    // LDS atomic
                    ebuf[p] = make_uint2(((unsigned)(r & 63) << 20) | (unsigned)(&cc.x)[j],
                                         (unsigned)__float_as_int((&vv.x)[j]));
                }
            }
            i4 = ni;
        }
    } else {
        gemm_body<DIN, HID, false, false, true>(X, Wp0, bn0, ab0, bg0,
            nullptr, nullptr, nullptr, nullptr, Hn0b, Hgb, n, blockIdx.x - NCHK * PF);
    }
}

template <int K, int HOUT, bool AFF, bool XBF, bool HNBF>
__global__ __launch_bounds__(256) void gemm_k(
    const void* __restrict__ X, const unsigned short* __restrict__ Wp,
    const float* __restrict__ bnA, const float* __restrict__ bnB, const float* __restrict__ bgA,
    const float* __restrict__ sums, const float* __restrict__ gamma, const float* __restrict__ beta,
    float* __restrict__ Hnf, unsigned short* __restrict__ Hnb, unsigned short* __restrict__ Hgb, int n)
{
    gemm_body<K, HOUT, AFF, XBF, HNBF>(X, Wp, bnA, bnB, bgA, sums, gamma, beta,
                                       Hnf, Hnb, Hgb, n, blockIdx.x);
}

// ---------------------------------------------------------------------------
// SpMM v2 (block-local CSR staging): each block owns 64 CONSECUTIVE rows;
// stages rowptr[65] + the block's whole edge segment (~512 edges) into LDS
// with coalesced loads; groups then read edges from LDS (broadcast,
// conflict-free) and issue only the Hgb gathers. Overflow (>1024 edges)
// falls back to direct global reads per row.
// ---------------------------------------------------------------------------

template <int HH, bool STATS, bool SBF, bool MARKED>
__global__ __launch_bounds__(256) void spmm_k(
    const int* __restrict__ rowptr, const int2* __restrict__ cs,
    const unsigned short* __restrict__ Hgb, void* __restrict__ Sv,
    float* __restrict__ stats, const int* __restrict__ mark, int n)
{
    constexpr int L   = HH / 4;     // lanes per group (16 or 8)
    constexpr int GP  = 256 / L;    // groups per block (16 or 32)
    constexpr int RPB = 64;         // rows per block (consecutive)
    constexpr int RPG = RPB / GP;   // rows per group (4 or 2)
    constexpr int ECAP = 1024;      // staged-edge capacity (8KB)
    __shared__ int2 es[ECAP];
    __shared__ int  rp[RPB + 1];

    const int t = threadIdx.x;
    const int R0 = blockIdx.x * RPB;
    if (t <= RPB) rp[t] = rowptr[min(R0 + t, n)];
    __syncthreads();
    const int e0b  = rp[0];
    const int scnt = min(rp[RPB] - e0b, ECAP);
    for (int i = t; i < scnt; i += 256) es[i] = cs[e0b + i];   // coalesced 8B
    __syncthreads();

    const int lane = t % L;
    const int g    = t / L;
    const int c0   = lane * 4;

    float4 sum = make_float4(0.f, 0.f, 0.f, 0.f);
    float4 sq  = make_float4(0.f, 0.f, 0.f, 0.f);

#define SPMM_ROW(FETCH)                                                            \
    {                                                                              \
        int e = le0;                                                               \
        for (; e + 3 < le1; e += 4) {                                              \
            int2 p0 = FETCH(e), p1 = FETCH(e + 1), p2 = FETCH(e + 2), p3 = FETCH(e + 3); \
            float v0 = __int_as_float(p0.y), v1 = __int_as_float(p1.y);            \
            float v2 = __int_as_float(p2.y), v3 = __int_as_float(p3.y);            \
            uint2 h0 = *(const uint2*)&Hgb[(size_t)p0.x * HH + c0];                \
            uint2 h1 = *(const uint2*)&Hgb[(size_t)p1.x * HH + c0];                \
            uint2 h2 = *(const uint2*)&Hgb[(size_t)p2.x * HH + c0];                \
            uint2 h3 = *(const uint2*)&Hgb[(size_t)p3.x * HH + c0];                \
            a0.x += v0 * bf2f_lo(h0.x); a0.y += v0 * bf2f_hi(h0.x);                \
            a0.z += v0 * bf2f_lo(h0.y); a0.w += v0 * bf2f_hi(h0.y);                \
            a1.x += v1 * bf2f_lo(h1.x); a1.y += v1 * bf2f_hi(h1.x);                \
            a1.z += v1 * bf2f_lo(h1.y); a1.w += v1 * bf2f_hi(h1.y);                \
            a2.x += v2 * bf2f_lo(h2.x); a2.y += v2 * bf2f_hi(h2.x);                \
            a2.z += v2 * bf2f_lo(h2.y); a2.w += v2 * bf2f_hi(h2.y);                \
            a3.x += v3 * bf2f_lo(h3.x); a3.y += v3 * bf2f_hi(h3.x);                \
            a3.z += v3 * bf2f_lo(h3.y); a3.w += v3 * bf2f_hi(h3.y);                \
        }                                                                          \
        for (; e < le1; e++) {                                                     \
            int2 p = FETCH(e);                                                     \
            float v = __int_as_float(p.y);                                         \
            uint2 h = *(const uint2*)&Hgb[(size_t)p.x * HH + c0];                  \
            a0.x += v * bf2f_lo(h.x); a0.y += v * bf2f_hi(h.x);                    \
            a0.z += v * bf2f_lo(h.y); a0.w += v * bf2f_hi(h.y);                    \
        }                                                                          \
    }
#define F_LDS(i) es[(i)]
#define F_GLB(i) cs[e0b + (i)]

#pragma unroll
    for (int rr = 0; rr < RPG; rr++) {
        int row = R0 + g * RPG + rr;
        if (row >= n) break;
        if (MARKED && !mark[row]) continue;
        int le0 = rp[g * RPG + rr] - e0b;
        int le1 = rp[g * RPG + rr + 1] - e0b;
        float4 a0, a1, a2, a3;
        if (SBF) {
            uint2 h = *(const uint2*)((const unsigned short*)Sv + (size_t)row * HH + c0);
            a0 = make_float4(bf2f_lo(h.x), bf2f_hi(h.x), bf2f_lo(h.y), bf2f_hi(h.y));
        } else {
            a0 = *(const float4*)((const float*)Sv + (size_t)row * HH + c0);
        }
        a1 = a2 = a3 = make_float4(0.f, 0.f, 0.f, 0.f);
        if (le1 <= scnt) SPMM_ROW(F_LDS) else SPMM_ROW(F_GLB);
        float4 acc = make_float4(a0.x + a1.x + a2.x + a3.x, a0.y + a1.y + a2.y + a3.y,
                                 a0.z + a1.z + a2.z + a3.z, a0.w + a1.w + a2.w + a3.w);
        if (SBF) {
            uint2 o;
            o.x = (unsigned)f2bf(acc.x) | ((unsigned)f2bf(acc.y) << 16);
            o.y = (unsigned)f2bf(acc.z) | ((unsigned)f2bf(acc.w) << 16);
            *(uint2*)((unsigned short*)Sv + (size_t)row * HH + c0) = o;
        } else {
            *(float4*)((float*)Sv + (size_t)row * HH + c0) = acc;
        }
        if (STATS) {
            sum.x += acc.x; sum.y += acc.y; sum.z += acc.z; sum.w += acc.w;
            sq.x += acc.x * acc.x; sq.y += acc.y * acc.y;
            sq.z += acc.z * acc.z; sq.w += acc.w * acc.w;
        }
    }
#undef SPMM_ROW
#undef F_LDS
#undef F_GLB

    if constexpr (STATS) {
        __shared__ float rs[GP][HH];
        __shared__ float rq[GP][HH];
        *(float4*)&rs[g][c0] = sum;
        *(float4*)&rq[g][c0] = sq;
        __syncthreads();
        if (threadIdx.x < HH) {
            float a = 0.f, b = 0.f;
            for (int w = 0; w < GP; w++) { a += rs[w][threadIdx.x]; b += rq[w][threadIdx.x]; }
            int stripe = blockIdx.x & 7;
            atomicAdd(&stats[stripe * 128 + threadIdx.x], a);
            atomicAdd(&stats[stripe * 128 + HH + threadIdx.x], b);
        }
    }
}

__global__ void gather_k(const float* __restrict__ S, const int* __restrict__ idx,
                         float* __restrict__ out, int total4) {
    int j = blockIdx.x * 256 + threadIdx.x;
    if (j < total4) {
        int r = j / (EMB / 4), c4 = (j % (EMB / 4)) * 4;
        *(float4*)&out[(size_t)j * 4] = *(const float4*)&S[(size_t)idx[r] * EMB + c4];
    }
}

// ---------------------------------------------------------------------------

extern "C" void kernel_launch(void* const* d_in, const int* in_sizes, int n_in,
                              void* d_out, int out_size, void* d_ws, size_t ws_size,
                              hipStream_t stream) {
    const float* features = (const float*)d_in[0];
    const int*   rows     = (const int*)d_in[1];
    const int*   cols     = (const int*)d_in[2];
    const float* vals     = (const float*)d_in[3];
    const int*   idx      = (const int*)d_in[4];
    const float* Wn0 = (const float*)d_in[5];
    const float* bn0 = (const float*)d_in[6];
    const float* Wg0 = (const float*)d_in[7];
    const float* bg0 = (const float*)d_in[8];
    const float* ab0 = (const float*)d_in[9];
    const float* g0  = (const float*)d_in[10];
    const float* b0  = (const float*)d_in[11];
    const float* Wn1 = (const float*)d_in[12];
    const float* Wg1 = (const float*)d_in[13];
    const float* ab1 = (const float*)d_in[14];
    const float* g1  = (const float*)d_in[15];
    const float* b1  = (const float*)d_in[16];
    const float* WnL = (const float*)d_in[17];
    const float* WgL = (const float*)d_in[18];
    const float* abL = (const float*)d_in[19];
    float* out = (float*)d_out;

    // Workspace layout (~65 MB), 16B-aligned sub-buffers.
    float*          HnLf = (float*)d_ws;                        // N x EMB fp32 (HnL/SL)
    unsigned short* nA   = (unsigned short*)(HnLf + (size_t)NNODES * EMB); // Hn0/S0 bf16
    unsigned short* nB   = nA + (size_t)NNODES * HID;           // Hn1/S1 bf16
    unsigned short* Hgb  = nB + (size_t)NNODES * HID;           // Hg (all layers) bf16
    uint2* ebuf  = (uint2*)(Hgb + (size_t)NNODES * HID);        // E x 8B (packed)
    int2*  cs    = (int2*)(ebuf + NEDGES);                      // E (row-sorted payload)
    int*   rowptr = (int*)(cs + NEDGES);                        // N+4
    int*   Bcnt4 = rowptr + (NNODES + 4);                       // NCHK x NB
    int*   BcntT = Bcnt4 + NCHK * NB;                           // NCHK x NB
    int*   bBase = BcntT + NCHK * NB;                           // NB+1 (pad 1568)
    unsigned short* Wp0 = (unsigned short*)(bBase + 1568);      // 16384
    unsigned short* Wp1 = Wp0 + 16384;                          // 8192
    unsigned short* WpL = Wp1 + 8192;                           // 4096
    // ---- single zeroed region: stats | mark | bTot ----
    float* stats = (float*)(WpL + 4096);                        // 2304
    int*   mark  = (int*)(stats + 2304);                        // N
    int*   bTot  = mark + NNODES;                               // 1568
    float* sums0 = stats;
    float* sums1 = stats + 1024;
    size_t zbytes = 2304 * 4 + (size_t)NNODES * 4 + 1568 * 4;

    hipMemsetAsync(stats, 0, zbytes, stream);

    const int GBm = (NNODES + 63) / 64;     // 1563
    const int MB  = (NIDX + 255) / 256;     // 196

    // K1: per-chunk bucket histogram (+bTot atomics) + mark + W pre-pack.
    histpack_k<<<NCHK + MB + 112, 256, 0, stream>>>(
        rows, Bcnt4, bTot, idx, mark, Wn0, Wg0, Wn1, Wg1, WnL, WgL, Wp0, Wp1, WpL, MB);
    // ONE dispatch: chunk-prefix (blocks 0-6) + bucket-base scan (block 7).
    scan_k<<<8, 256, 0, stream>>>(Bcnt4, BcntT, bTot, bBase);
    part_gemm0_k<<<NCHK * PF + GBm, 256, 0, stream>>>(rows, cols, vals, BcntT, bBase, ebuf,
                                                      features, Wp0, bn0, ab0, bg0,
                                                      nA, Hgb, NNODES);
    // FUSED v2: single-pass bucket sort (LDS) -> rowptr/cs AND S0 = Hn0 + A@Hg0
    bfinal_spmm0_k<<<NB, 256, 0, stream>>>(ebuf, bBase, rowptr, cs, Hgb, nA, sums0, NNODES);

    // Layer 1: BN finalize folded into gemm; S1 = Hn1 + ab1 + A@Hg1
    gemm_k<HID, HID, true, true, true><<<GBm, 256, 0, stream>>>(
        nA, Wp1, ab1, nullptr, nullptr, sums0, g0, b0, nullptr, nB, Hgb, NNODES);
    spmm_k<HID, true, true, false><<<GBm, 256, 0, stream>>>(rowptr, cs, Hgb, nB, sums1, nullptr, NNODES);

    // Last layer: HnL fp32; aggregate only rows referenced by idx.
    gemm_k<HID, EMB, true, true, false><<<GBm, 256, 0, stream>>>(
        nB, WpL, abL, nullptr, nullptr, sums1, g1, b1, HnLf, nullptr, Hgb, NNODES);
    spmm_k<EMB, false, false, true><<<GBm, 256, 0, stream>>>(rowptr, cs, Hgb, HnLf, nullptr, mark, NNODES);

    gather_k<<<(NIDX * EMB / 4 + 255) / 256, 256, 0, stream>>>(HnLf, idx, out, NIDX * EMB / 4);
}